// Round 1
// baseline (256.436 us; speedup 1.0000x reference)
//
#include <hip/hip_runtime.h>

#define BB 8
#define CC 128

// ---------------- inLay channel combine (Ci=3) ----------------
__global__ __launch_bounds__(256) void combine3_kernel(
    const float* __restrict__ lin, const float* __restrict__ x, float* __restrict__ y) {
  const int HW = 4096;
  int p = blockIdx.x * 256 + threadIdx.x;   // grid.x = 16 -> exactly HW
  int c = blockIdx.y;
  int b = blockIdx.z;
  const float* xb = x + (size_t)b * 3 * HW;
  float w0 = lin[c * 3 + 0], w1 = lin[c * 3 + 1], w2 = lin[c * 3 + 2];
  y[((size_t)b * CC + c) * HW + p] = w0 * xb[p] + w1 * xb[HW + p] + w2 * xb[2 * HW + p];
}

// ---------------- channel combine GEMM: y[b] = lin(128x128) * x[b](128xHW) --------
__global__ __launch_bounds__(256) void gemm_kernel(
    const float* __restrict__ lin, const float* __restrict__ x,
    float* __restrict__ y, int HW) {
  const int Ci = 128;
  __shared__ float As[16][65];
  __shared__ float Bs[16][64];
  int b = blockIdx.z;
  const float* xb = x + (size_t)b * Ci * HW;
  float* yb = y + (size_t)b * CC * HW;
  int tid = threadIdx.x;
  int tx = tid & 15, ty = tid >> 4;
  int row0 = blockIdx.y * 64;   // output channel tile
  int col0 = blockIdx.x * 64;   // pixel tile
  float acc[4][4] = {};
  for (int k0 = 0; k0 < Ci; k0 += 16) {
    // A tile: 64 rows (c) x 16 k; index so consecutive threads read consecutive k
    for (int l = tid; l < 64 * 16; l += 256) {
      int kk = l & 15, m = l >> 4;
      As[kk][m] = lin[(row0 + m) * Ci + k0 + kk];
    }
    // B tile: 16 k x 64 px, coalesced in px
    for (int l = tid; l < 16 * 64; l += 256) {
      int n = l & 63, kk = l >> 6;
      Bs[kk][n] = xb[(size_t)(k0 + kk) * HW + col0 + n];
    }
    __syncthreads();
#pragma unroll
    for (int kk = 0; kk < 16; ++kk) {
      float a[4], bv[4];
#pragma unroll
      for (int i = 0; i < 4; i++) a[i] = As[kk][ty * 4 + i];
#pragma unroll
      for (int j = 0; j < 4; j++) bv[j] = Bs[kk][tx * 4 + j];
#pragma unroll
      for (int i = 0; i < 4; i++)
#pragma unroll
        for (int j = 0; j < 4; j++) acc[i][j] += a[i] * bv[j];
    }
    __syncthreads();
  }
#pragma unroll
  for (int i = 0; i < 4; i++) {
    float* yr = yb + (size_t)(row0 + ty * 4 + i) * HW + col0 + tx * 4;
#pragma unroll
    for (int j = 0; j < 4; j++) yr[j] = acc[i][j];
  }
}

// ---------------- fused affine_grid + grid_sample + box mask ----------------
__global__ __launch_bounds__(256) void sample_kernel(
    const float* __restrict__ y, const float* __restrict__ geo,
    const float* __restrict__ box, float* __restrict__ out, int H, int W) {
  int c = blockIdx.y, b = blockIdx.z;
  int tid = threadIdx.x;
  int w = tid % W;
  int rows = 256 / W;
  int h = blockIdx.x * rows + tid / W;

  float xs = (2.0f * w + 1.0f) / W - 1.0f;
  float ys = (2.0f * h + 1.0f) / H - 1.0f;
  const float* g = geo + c * 6;
  const float* bx = box + c * 6;

  // geo sample
  float gx = g[0] * xs + g[1] * ys + g[2];
  float gy = g[3] * xs + g[4] * ys + g[5];
  float ix = ((gx + 1.0f) * W - 1.0f) * 0.5f;
  float iy = ((gy + 1.0f) * H - 1.0f) * 0.5f;
  float x0 = floorf(ix), y0 = floorf(iy);
  float wx = ix - x0, wy = iy - y0;
  const float* plane = y + ((size_t)b * CC + c) * H * W;
  float v[2][2];
#pragma unroll
  for (int dy = 0; dy < 2; ++dy)
#pragma unroll
    for (int dx = 0; dx < 2; ++dx) {
      float xf = x0 + dx, yf = y0 + dy;
      bool valid = (xf >= 0.0f) && (xf <= (float)(W - 1)) && (yf >= 0.0f) && (yf <= (float)(H - 1));
      int xi = (int)fminf(fmaxf(xf, 0.0f), (float)(W - 1));
      int yi = (int)fminf(fmaxf(yf, 0.0f), (float)(H - 1));
      v[dy][dx] = valid ? plane[yi * W + xi] : 0.0f;
    }
  float samp = (1.0f - wy) * ((1.0f - wx) * v[0][0] + wx * v[0][1]) +
               wy * ((1.0f - wx) * v[1][0] + wx * v[1][1]);

  // box mask (grid_sample of ones image)
  float bgx = bx[0] * xs + bx[1] * ys + bx[2];
  float bgy = bx[3] * xs + bx[4] * ys + bx[5];
  float bix = ((bgx + 1.0f) * W - 1.0f) * 0.5f;
  float biy = ((bgy + 1.0f) * H - 1.0f) * 0.5f;
  float bx0 = floorf(bix), by0 = floorf(biy);
  float bwx = bix - bx0, bwy = biy - by0;
  float m[2][2];
#pragma unroll
  for (int dy = 0; dy < 2; ++dy)
#pragma unroll
    for (int dx = 0; dx < 2; ++dx) {
      float xf = bx0 + dx, yf = by0 + dy;
      m[dy][dx] = ((xf >= 0.0f) && (xf <= (float)(W - 1)) && (yf >= 0.0f) && (yf <= (float)(H - 1)))
                      ? 1.0f : 0.0f;
    }
  float mask = (1.0f - bwy) * ((1.0f - bwx) * m[0][0] + bwx * m[0][1]) +
               bwy * ((1.0f - bwx) * m[1][0] + bwx * m[1][1]);

  out[((size_t)b * CC + c) * H * W + h * W + w] = samp * mask;
}

// ---------------- MaxPool2d_G: 64x64 -> 32x32 window gather around box-filter argmax ----
__global__ __launch_bounds__(256) void maxpool_kernel(
    const float* __restrict__ x, float* __restrict__ out) {
  __shared__ float xs[64 * 64];
  __shared__ float cb[64 * 64];
  __shared__ float rval[256];
  __shared__ int ridx[256];
  int bc = blockIdx.x;
  int tid = threadIdx.x;
  const float* plane = x + (size_t)bc * 4096;
  for (int i = tid; i < 4096; i += 256) xs[i] = plane[i];
  __syncthreads();
  // column band sums: cb[h][w] = sum_{r=h-16..h+15, clipped} xs[r][w]
  for (int i = tid; i < 4096; i += 256) {
    int h = i >> 6, w = i & 63;
    int lo = h - 16; if (lo < 0) lo = 0;
    int hi = h + 15; if (hi > 63) hi = 63;
    float s = 0.0f;
    for (int r = lo; r <= hi; ++r) s += xs[(r << 6) + w];
    cb[i] = s;
  }
  __syncthreads();
  // window sums + argmax (first occurrence of max, row-major)
  float best = -3.402823466e+38f;
  int bidx = 0x7fffffff;
  for (int i = tid; i < 4096; i += 256) {
    int h = i >> 6, w = i & 63;
    int lo = w - 16; if (lo < 0) lo = 0;
    int hi = w + 15; if (hi > 63) hi = 63;
    float s = 0.0f;
    for (int cc = lo; cc <= hi; ++cc) s += cb[(h << 6) + cc];
    if (s > best) { best = s; bidx = i; }  // per-thread indices ascending -> keeps first
  }
  rval[tid] = best; ridx[tid] = bidx;
  __syncthreads();
  for (int s = 128; s > 0; s >>= 1) {
    if (tid < s) {
      float v2 = rval[tid + s]; int i2 = ridx[tid + s];
      if (v2 > rval[tid] || (v2 == rval[tid] && i2 < ridx[tid])) { rval[tid] = v2; ridx[tid] = i2; }
    }
    __syncthreads();
  }
  int am = ridx[0];
  int r = am >> 6, c = am & 63;
  float* o = out + (size_t)bc * 1024;
  for (int i = tid; i < 1024; i += 256) {
    int oi = i >> 5, oj = i & 31;
    int rr = r + oi - 16, cj = c + oj - 16;
    o[i] = (rr >= 0 && rr < 64 && cj >= 0 && cj < 64) ? xs[(rr << 6) + cj] : 0.0f;
  }
}

// ---------------- mean pool over H,W ----------------
__global__ __launch_bounds__(256) void pool_kernel(
    const float* __restrict__ feat, float* __restrict__ pooled) {
  int bc = blockIdx.x;
  const float* p = feat + (size_t)bc * 1024;
  int tid = threadIdx.x;
  float s = p[tid] + p[tid + 256] + p[tid + 512] + p[tid + 768];
  __shared__ float sm[256];
  sm[tid] = s;
  __syncthreads();
  for (int st = 128; st > 0; st >>= 1) {
    if (tid < st) sm[tid] += sm[tid + st];
    __syncthreads();
  }
  if (tid == 0) pooled[bc] = sm[0] * (1.0f / 1024.0f);
}

// ---------------- dense head ----------------
__global__ __launch_bounds__(128) void dense_kernel(
    const float* __restrict__ pooled, const float* __restrict__ w,
    const float* __restrict__ bias, float* __restrict__ out) {
  int t = threadIdx.x;
  if (t < 80) {
    int b = t / 10, o = t % 10;
    float s = bias[o];
    const float* pb = pooled + b * 128;
    const float* wo = w + o * 128;
    for (int c = 0; c < 128; ++c) s += pb[c] * wo[c];
    out[b * 10 + o] = s;
  }
}

extern "C" void kernel_launch(void* const* d_in, const int* in_sizes, int n_in,
                              void* d_out, int out_size, void* d_ws, size_t ws_size,
                              hipStream_t stream) {
  const float* x     = (const float*)d_in[0];   // [8,3,64,64]
  const float* geo0  = (const float*)d_in[1];   // [128,2,3]
  const float* lin0  = (const float*)d_in[2];   // [128,3]
  const float* box0  = (const float*)d_in[3];   // [128,2,3]
  const float* geos  = (const float*)d_in[4];   // [3,128,2,3]
  const float* lins  = (const float*)d_in[5];   // [3,128,128]
  const float* boxes = (const float*)d_in[6];   // [3,128,2,3]
  const float* dw    = (const float*)d_in[7];   // [10,128]
  const float* db    = (const float*)d_in[8];   // [10]

  float* out  = (float*)d_out;      // [8,10] then feat [8,128,32,32]
  float* feat = out + 80;
  float* ws   = (float*)d_ws;
  float* ws0  = ws;                 // 16 MB
  float* ws1  = ws + 4194304;       // 16 MB
  float* pooled = ws + 8388608;     // 1024 floats

  // inLay: combine (Ci=3) -> sample
  combine3_kernel<<<dim3(16, CC, BB), 256, 0, stream>>>(lin0, x, ws0);
  sample_kernel<<<dim3(16, CC, BB), 256, 0, stream>>>(ws0, geo0, box0, ws1, 64, 64);
  // layer 0: combine -> sample (64x64)
  gemm_kernel<<<dim3(64, 2, BB), 256, 0, stream>>>(lins, ws1, ws0, 4096);
  sample_kernel<<<dim3(16, CC, BB), 256, 0, stream>>>(ws0, geos, boxes, ws1, 64, 64);
  // layer 1: maxpool_g -> [8,128,32,32]
  maxpool_kernel<<<dim3(BB * CC), 256, 0, stream>>>(ws1, ws0);
  // layer 2: combine -> sample (32x32)
  gemm_kernel<<<dim3(16, 2, BB), 256, 0, stream>>>(lins + 16384, ws0, ws1, 1024);
  sample_kernel<<<dim3(4, CC, BB), 256, 0, stream>>>(ws1, geos + 768, boxes + 768, ws0, 32, 32);
  // layer 3: combine -> sample (32x32), feat straight to d_out
  gemm_kernel<<<dim3(16, 2, BB), 256, 0, stream>>>(lins + 32768, ws0, ws1, 1024);
  sample_kernel<<<dim3(4, CC, BB), 256, 0, stream>>>(ws1, geos + 1536, boxes + 1536, feat, 32, 32);
  // head
  pool_kernel<<<dim3(BB * CC), 256, 0, stream>>>(feat, pooled);
  dense_kernel<<<1, 128, 0, stream>>>(pooled, dw, db, out);
}

// Round 2
// 203.581 us; speedup vs baseline: 1.2596x; 1.2596x over previous
//
#include <hip/hip_runtime.h>

#define BB 8
#define CC 128

// ---------------- fused inLay: channel combine (Ci=3) + affine sample + box mask ----
__global__ __launch_bounds__(256) void inlay_sample_kernel(
    const float* __restrict__ x, const float* __restrict__ lin,
    const float* __restrict__ geo, const float* __restrict__ box,
    float* __restrict__ out) {
  const int H = 64, W = 64, HW = 4096;
  int c = blockIdx.y, b = blockIdx.z;
  int tid = threadIdx.x;
  int w = tid & 63;
  int h = blockIdx.x * 4 + (tid >> 6);

  const float* xb = x + (size_t)b * 3 * HW;
  float w0 = lin[c * 3 + 0], w1 = lin[c * 3 + 1], w2 = lin[c * 3 + 2];

  float xs = (2.0f * w + 1.0f) / W - 1.0f;
  float ys = (2.0f * h + 1.0f) / H - 1.0f;
  const float* g = geo + c * 6;
  const float* bx = box + c * 6;

  float gx = g[0] * xs + g[1] * ys + g[2];
  float gy = g[3] * xs + g[4] * ys + g[5];
  float ix = ((gx + 1.0f) * W - 1.0f) * 0.5f;
  float iy = ((gy + 1.0f) * H - 1.0f) * 0.5f;
  float x0 = floorf(ix), y0 = floorf(iy);
  float wx = ix - x0, wy = iy - y0;
  float v[2][2];
#pragma unroll
  for (int dy = 0; dy < 2; ++dy)
#pragma unroll
    for (int dx = 0; dx < 2; ++dx) {
      float xf = x0 + dx, yf = y0 + dy;
      bool valid = (xf >= 0.0f) && (xf <= (float)(W - 1)) && (yf >= 0.0f) && (yf <= (float)(H - 1));
      int xi = (int)fminf(fmaxf(xf, 0.0f), (float)(W - 1));
      int yi = (int)fminf(fmaxf(yf, 0.0f), (float)(H - 1));
      int t = yi * W + xi;
      float vv = w0 * xb[t] + w1 * xb[HW + t] + w2 * xb[2 * HW + t];
      v[dy][dx] = valid ? vv : 0.0f;
    }
  float samp = (1.0f - wy) * ((1.0f - wx) * v[0][0] + wx * v[0][1]) +
               wy * ((1.0f - wx) * v[1][0] + wx * v[1][1]);

  float bgx = bx[0] * xs + bx[1] * ys + bx[2];
  float bgy = bx[3] * xs + bx[4] * ys + bx[5];
  float bix = ((bgx + 1.0f) * W - 1.0f) * 0.5f;
  float biy = ((bgy + 1.0f) * H - 1.0f) * 0.5f;
  float bx0 = floorf(bix), by0 = floorf(biy);
  float bwx = bix - bx0, bwy = biy - by0;
  float m[2][2];
#pragma unroll
  for (int dy = 0; dy < 2; ++dy)
#pragma unroll
    for (int dx = 0; dx < 2; ++dx) {
      float xf = bx0 + dx, yf = by0 + dy;
      m[dy][dx] = ((xf >= 0.0f) && (xf <= (float)(W - 1)) && (yf >= 0.0f) && (yf <= (float)(H - 1)))
                      ? 1.0f : 0.0f;
    }
  float mask = (1.0f - bwy) * ((1.0f - bwx) * m[0][0] + bwx * m[0][1]) +
               bwy * ((1.0f - bwx) * m[1][0] + bwx * m[1][1]);

  out[((size_t)b * CC + c) * HW + h * W + w] = samp * mask;
}

// ---------------- channel combine GEMM: y[b] = lin(128x128) * x[b](128xHW) --------
__global__ __launch_bounds__(256) void gemm_kernel(
    const float* __restrict__ lin, const float* __restrict__ x,
    float* __restrict__ y, int HW) {
  const int Ci = 128;
  __shared__ __align__(16) float As[16][68];   // row stride 272 B (16B-aligned)
  __shared__ __align__(16) float Bs[16][64];
  int b = blockIdx.z;
  const float* xb = x + (size_t)b * Ci * HW;
  float* yb = y + (size_t)b * CC * HW;
  int tid = threadIdx.x;
  int tx = tid & 15, ty = tid >> 4;
  int row0 = blockIdx.y * 64;
  int col0 = blockIdx.x * 64;
  float acc[4][4] = {};
  for (int k0 = 0; k0 < Ci; k0 += 16) {
    // A tile: float4 along k, transpose-store into As[k][m]
    {
      int m = tid >> 2, kq = (tid & 3) * 4;
      float4 av = *reinterpret_cast<const float4*>(&lin[(row0 + m) * Ci + k0 + kq]);
      As[kq + 0][m] = av.x; As[kq + 1][m] = av.y; As[kq + 2][m] = av.z; As[kq + 3][m] = av.w;
    }
    // B tile: float4 along pixels, coalesced
    {
      int kk = tid >> 4, n4 = (tid & 15) * 4;
      *reinterpret_cast<float4*>(&Bs[kk][n4]) =
          *reinterpret_cast<const float4*>(&xb[(size_t)(k0 + kk) * HW + col0 + n4]);
    }
    __syncthreads();
#pragma unroll
    for (int kk = 0; kk < 16; ++kk) {
      float4 a4 = *reinterpret_cast<const float4*>(&As[kk][ty * 4]);
      float4 b4 = *reinterpret_cast<const float4*>(&Bs[kk][tx * 4]);
      float a[4] = {a4.x, a4.y, a4.z, a4.w};
      float bv[4] = {b4.x, b4.y, b4.z, b4.w};
#pragma unroll
      for (int i = 0; i < 4; i++)
#pragma unroll
        for (int j = 0; j < 4; j++) acc[i][j] += a[i] * bv[j];
    }
    __syncthreads();
  }
#pragma unroll
  for (int i = 0; i < 4; i++) {
    float* yr = yb + (size_t)(row0 + ty * 4 + i) * HW + col0 + tx * 4;
    *reinterpret_cast<float4*>(yr) = make_float4(acc[i][0], acc[i][1], acc[i][2], acc[i][3]);
  }
}

// ---------------- affine sample + box mask, LDS-staged plane, one block per (b,c) ----
template <int H, int W>
__global__ __launch_bounds__(256) void sample_kernel(
    const float* __restrict__ y, const float* __restrict__ geo,
    const float* __restrict__ box, float* __restrict__ out) {
  constexpr int HW = H * W;
  constexpr int PXT = HW / 256;
  __shared__ __align__(16) float pl[HW];
  int c = blockIdx.x & (CC - 1);
  int b = blockIdx.x >> 7;
  int tid = threadIdx.x;
  const float* plane = y + ((size_t)b * CC + c) * HW;
#pragma unroll
  for (int k = 0; k < PXT / 4; ++k) {
    int i4 = tid + k * 256;
    *reinterpret_cast<float4*>(&pl[i4 * 4]) = *reinterpret_cast<const float4*>(&plane[i4 * 4]);
  }
  __syncthreads();

  const float* g = geo + c * 6;
  const float* bx = box + c * 6;
  float g0 = g[0], g1 = g[1], g2 = g[2], g3 = g[3], g4 = g[4], g5 = g[5];
  float b0 = bx[0], b1 = bx[1], b2 = bx[2], b3 = bx[3], b4 = bx[4], b5 = bx[5];
  float* o = out + ((size_t)b * CC + c) * HW;

#pragma unroll
  for (int k = 0; k < PXT; ++k) {
    int px = tid + k * 256;
    int h = px / W, w = px % W;
    float xs = (2.0f * w + 1.0f) / W - 1.0f;
    float ys = (2.0f * h + 1.0f) / H - 1.0f;

    float gx = g0 * xs + g1 * ys + g2;
    float gy = g3 * xs + g4 * ys + g5;
    float ix = ((gx + 1.0f) * W - 1.0f) * 0.5f;
    float iy = ((gy + 1.0f) * H - 1.0f) * 0.5f;
    float x0 = floorf(ix), y0 = floorf(iy);
    float wx = ix - x0, wy = iy - y0;
    float v[2][2];
#pragma unroll
    for (int dy = 0; dy < 2; ++dy)
#pragma unroll
      for (int dx = 0; dx < 2; ++dx) {
        float xf = x0 + dx, yf = y0 + dy;
        bool valid = (xf >= 0.0f) && (xf <= (float)(W - 1)) && (yf >= 0.0f) && (yf <= (float)(H - 1));
        int xi = (int)fminf(fmaxf(xf, 0.0f), (float)(W - 1));
        int yi = (int)fminf(fmaxf(yf, 0.0f), (float)(H - 1));
        v[dy][dx] = valid ? pl[yi * W + xi] : 0.0f;
      }
    float samp = (1.0f - wy) * ((1.0f - wx) * v[0][0] + wx * v[0][1]) +
                 wy * ((1.0f - wx) * v[1][0] + wx * v[1][1]);

    float bgx = b0 * xs + b1 * ys + b2;
    float bgy = b3 * xs + b4 * ys + b5;
    float bix = ((bgx + 1.0f) * W - 1.0f) * 0.5f;
    float biy = ((bgy + 1.0f) * H - 1.0f) * 0.5f;
    float bx0 = floorf(bix), by0 = floorf(biy);
    float bwx = bix - bx0, bwy = biy - by0;
    float m[2][2];
#pragma unroll
    for (int dy = 0; dy < 2; ++dy)
#pragma unroll
      for (int dx = 0; dx < 2; ++dx) {
        float xf = bx0 + dx, yf = by0 + dy;
        m[dy][dx] = ((xf >= 0.0f) && (xf <= (float)(W - 1)) && (yf >= 0.0f) && (yf <= (float)(H - 1)))
                        ? 1.0f : 0.0f;
      }
    float mask = (1.0f - bwy) * ((1.0f - bwx) * m[0][0] + bwx * m[0][1]) +
                 bwy * ((1.0f - bwx) * m[1][0] + bwx * m[1][1]);

    o[px] = samp * mask;
  }
}

// ---------------- MaxPool2d_G, 1024 threads, bit-identical sums to round-1 ----------
__global__ __launch_bounds__(1024) void maxpool_kernel(
    const float* __restrict__ x, float* __restrict__ out) {
  __shared__ __align__(16) float xs[4096];
  __shared__ __align__(16) float cb[4096];
  __shared__ float wv[16];
  __shared__ int wi[16];
  __shared__ int am_s;
  int bc = blockIdx.x;
  int tid = threadIdx.x;
  const float* plane = x + (size_t)bc * 4096;
  *reinterpret_cast<float4*>(&xs[tid * 4]) = *reinterpret_cast<const float4*>(&plane[tid * 4]);
  __syncthreads();
  // column band sums (same per-element order as round 1: r ascending)
#pragma unroll
  for (int k = 0; k < 4; ++k) {
    int i = tid + k * 1024;
    int h = i >> 6, w = i & 63;
    int lo = h - 16; if (lo < 0) lo = 0;
    int hi = h + 15; if (hi > 63) hi = 63;
    float s = 0.0f;
    for (int r = lo; r <= hi; ++r) s += xs[(r << 6) + w];
    cb[i] = s;
  }
  __syncthreads();
  // window sums + argmax (first-occurrence tie rule, partition-invariant)
  float best = -3.402823466e+38f;
  int bidx = 0x7fffffff;
#pragma unroll
  for (int k = 0; k < 4; ++k) {
    int i = tid + k * 1024;
    int h = i >> 6, w = i & 63;
    int lo = w - 16; if (lo < 0) lo = 0;
    int hi = w + 15; if (hi > 63) hi = 63;
    float s = 0.0f;
    for (int cc = lo; cc <= hi; ++cc) s += cb[(h << 6) + cc];
    if (s > best) { best = s; bidx = i; }
  }
  // wave reduction (64 lanes)
#pragma unroll
  for (int off = 32; off > 0; off >>= 1) {
    float v2 = __shfl_down(best, off);
    int i2 = __shfl_down(bidx, off);
    if (v2 > best || (v2 == best && i2 < bidx)) { best = v2; bidx = i2; }
  }
  if ((tid & 63) == 0) { wv[tid >> 6] = best; wi[tid >> 6] = bidx; }
  __syncthreads();
  if (tid == 0) {
    float bv = wv[0]; int bi = wi[0];
    for (int k = 1; k < 16; ++k) {
      if (wv[k] > bv || (wv[k] == bv && wi[k] < bi)) { bv = wv[k]; bi = wi[k]; }
    }
    am_s = bi;
  }
  __syncthreads();
  int am = am_s;
  int r = am >> 6, c = am & 63;
  float* o = out + (size_t)bc * 1024;
  {
    int oi = tid >> 5, oj = tid & 31;
    int rr = r + oi - 16, cj = c + oj - 16;
    o[tid] = (rr >= 0 && rr < 64 && cj >= 0 && cj < 64) ? xs[(rr << 6) + cj] : 0.0f;
  }
}

// ---------------- mean pool over H,W ----------------
__global__ __launch_bounds__(256) void pool_kernel(
    const float* __restrict__ feat, float* __restrict__ pooled) {
  int bc = blockIdx.x;
  const float* p = feat + (size_t)bc * 1024;
  int tid = threadIdx.x;
  float s = p[tid] + p[tid + 256] + p[tid + 512] + p[tid + 768];
  __shared__ float sm[256];
  sm[tid] = s;
  __syncthreads();
  for (int st = 128; st > 0; st >>= 1) {
    if (tid < st) sm[tid] += sm[tid + st];
    __syncthreads();
  }
  if (tid == 0) pooled[bc] = sm[0] * (1.0f / 1024.0f);
}

// ---------------- dense head ----------------
__global__ __launch_bounds__(128) void dense_kernel(
    const float* __restrict__ pooled, const float* __restrict__ w,
    const float* __restrict__ bias, float* __restrict__ out) {
  int t = threadIdx.x;
  if (t < 80) {
    int b = t / 10, o = t % 10;
    float s = bias[o];
    const float* pb = pooled + b * 128;
    const float* wo = w + o * 128;
    for (int c = 0; c < 128; ++c) s += pb[c] * wo[c];
    out[b * 10 + o] = s;
  }
}

extern "C" void kernel_launch(void* const* d_in, const int* in_sizes, int n_in,
                              void* d_out, int out_size, void* d_ws, size_t ws_size,
                              hipStream_t stream) {
  const float* x     = (const float*)d_in[0];   // [8,3,64,64]
  const float* geo0  = (const float*)d_in[1];   // [128,2,3]
  const float* lin0  = (const float*)d_in[2];   // [128,3]
  const float* box0  = (const float*)d_in[3];   // [128,2,3]
  const float* geos  = (const float*)d_in[4];   // [3,128,2,3]
  const float* lins  = (const float*)d_in[5];   // [3,128,128]
  const float* boxes = (const float*)d_in[6];   // [3,128,2,3]
  const float* dw    = (const float*)d_in[7];   // [10,128]
  const float* db    = (const float*)d_in[8];   // [10]

  float* out  = (float*)d_out;      // [8,10] then feat [8,128,32,32]
  float* feat = out + 80;
  float* ws   = (float*)d_ws;
  float* ws0  = ws;                 // 16 MB
  float* ws1  = ws + 4194304;       // 16 MB
  float* pooled = ws + 8388608;     // 1024 floats

  // inLay: fused combine(Ci=3) + sample -> ws1
  inlay_sample_kernel<<<dim3(16, CC, BB), 256, 0, stream>>>(x, lin0, geo0, box0, ws1);
  // layer 0: combine -> sample (64x64)
  gemm_kernel<<<dim3(64, 2, BB), 256, 0, stream>>>(lins, ws1, ws0, 4096);
  sample_kernel<64, 64><<<dim3(BB * CC), 256, 0, stream>>>(ws0, geos, boxes, ws1);
  // layer 1: maxpool_g -> [8,128,32,32]
  maxpool_kernel<<<dim3(BB * CC), 1024, 0, stream>>>(ws1, ws0);
  // layer 2: combine -> sample (32x32)
  gemm_kernel<<<dim3(16, 2, BB), 256, 0, stream>>>(lins + 16384, ws0, ws1, 1024);
  sample_kernel<32, 32><<<dim3(BB * CC), 256, 0, stream>>>(ws1, geos + 768, boxes + 768, ws0);
  // layer 3: combine -> sample (32x32), feat straight to d_out
  gemm_kernel<<<dim3(16, 2, BB), 256, 0, stream>>>(lins + 32768, ws0, ws1, 1024);
  sample_kernel<32, 32><<<dim3(BB * CC), 256, 0, stream>>>(ws1, geos + 1536, boxes + 1536, feat);
  // head
  pool_kernel<<<dim3(BB * CC), 256, 0, stream>>>(feat, pooled);
  dense_kernel<<<1, 128, 0, stream>>>(pooled, dw, db, out);
}

// Round 3
// 186.292 us; speedup vs baseline: 1.3765x; 1.0928x over previous
//
#include <hip/hip_runtime.h>

#define BB 8
#define CC 128

// ---------------- fused inLay: channel combine (Ci=3) + affine sample + box mask ----
__global__ __launch_bounds__(256) void inlay_sample_kernel(
    const float* __restrict__ x, const float* __restrict__ lin,
    const float* __restrict__ geo, const float* __restrict__ box,
    float* __restrict__ out) {
  const int H = 64, W = 64, HW = 4096;
  int c = blockIdx.y, b = blockIdx.z;
  int tid = threadIdx.x;
  int w = tid & 63;
  int h = blockIdx.x * 4 + (tid >> 6);

  const float* xb = x + (size_t)b * 3 * HW;
  float w0 = lin[c * 3 + 0], w1 = lin[c * 3 + 1], w2 = lin[c * 3 + 2];

  float xs = (2.0f * w + 1.0f) / W - 1.0f;
  float ys = (2.0f * h + 1.0f) / H - 1.0f;
  const float* g = geo + c * 6;
  const float* bx = box + c * 6;

  float gx = g[0] * xs + g[1] * ys + g[2];
  float gy = g[3] * xs + g[4] * ys + g[5];
  float ix = ((gx + 1.0f) * W - 1.0f) * 0.5f;
  float iy = ((gy + 1.0f) * H - 1.0f) * 0.5f;
  float x0 = floorf(ix), y0 = floorf(iy);
  float wx = ix - x0, wy = iy - y0;
  float v[2][2];
#pragma unroll
  for (int dy = 0; dy < 2; ++dy)
#pragma unroll
    for (int dx = 0; dx < 2; ++dx) {
      float xf = x0 + dx, yf = y0 + dy;
      bool valid = (xf >= 0.0f) && (xf <= (float)(W - 1)) && (yf >= 0.0f) && (yf <= (float)(H - 1));
      int xi = (int)fminf(fmaxf(xf, 0.0f), (float)(W - 1));
      int yi = (int)fminf(fmaxf(yf, 0.0f), (float)(H - 1));
      int t = yi * W + xi;
      float vv = w0 * xb[t] + w1 * xb[HW + t] + w2 * xb[2 * HW + t];
      v[dy][dx] = valid ? vv : 0.0f;
    }
  float samp = (1.0f - wy) * ((1.0f - wx) * v[0][0] + wx * v[0][1]) +
               wy * ((1.0f - wx) * v[1][0] + wx * v[1][1]);

  float bgx = bx[0] * xs + bx[1] * ys + bx[2];
  float bgy = bx[3] * xs + bx[4] * ys + bx[5];
  float bix = ((bgx + 1.0f) * W - 1.0f) * 0.5f;
  float biy = ((bgy + 1.0f) * H - 1.0f) * 0.5f;
  float bx0 = floorf(bix), by0 = floorf(biy);
  float bwx = bix - bx0, bwy = biy - by0;
  float m[2][2];
#pragma unroll
  for (int dy = 0; dy < 2; ++dy)
#pragma unroll
    for (int dx = 0; dx < 2; ++dx) {
      float xf = bx0 + dx, yf = by0 + dy;
      m[dy][dx] = ((xf >= 0.0f) && (xf <= (float)(W - 1)) && (yf >= 0.0f) && (yf <= (float)(H - 1)))
                      ? 1.0f : 0.0f;
    }
  float mask = (1.0f - bwy) * ((1.0f - bwx) * m[0][0] + bwx * m[0][1]) +
               bwy * ((1.0f - bwx) * m[1][0] + bwx * m[1][1]);

  out[((size_t)b * CC + c) * HW + h * W + w] = samp * mask;
}

// ---------------- big GEMM: 128x128 block tile, 8x8 per thread (layer0, HW=4096) ----
__global__ __launch_bounds__(256) void gemm128_kernel(
    const float* __restrict__ lin, const float* __restrict__ x,
    float* __restrict__ y, int HW) {
  const int Ci = 128;
  __shared__ __align__(16) float As[16][132];
  __shared__ __align__(16) float Bs[16][128];
  int b = blockIdx.z;
  const float* xb = x + (size_t)b * Ci * HW;
  float* yb = y + (size_t)b * CC * HW;
  int tid = threadIdx.x;
  int tx = tid & 15, ty = tid >> 4;
  int col0 = blockIdx.x * 128;
  float acc[8][8] = {};
  float4 ra[2], rb[2];

  // prologue: prefetch k0=0 tiles into registers
#pragma unroll
  for (int q = 0; q < 2; ++q) {
    int l = tid + q * 256;
    int m = l >> 2, kq = (l & 3) * 4;
    ra[q] = *reinterpret_cast<const float4*>(&lin[m * Ci + kq]);
    int kk = l >> 5, n4 = (l & 31) * 4;
    rb[q] = *reinterpret_cast<const float4*>(&xb[(size_t)kk * HW + col0 + n4]);
  }
  for (int k0 = 0; k0 < 128; k0 += 16) {
    __syncthreads();   // previous compute done before LDS overwrite
#pragma unroll
    for (int q = 0; q < 2; ++q) {
      int l = tid + q * 256;
      int m = l >> 2, kq = (l & 3) * 4;
      As[kq + 0][m] = ra[q].x; As[kq + 1][m] = ra[q].y;
      As[kq + 2][m] = ra[q].z; As[kq + 3][m] = ra[q].w;
      int kk = l >> 5, n4 = (l & 31) * 4;
      *reinterpret_cast<float4*>(&Bs[kk][n4]) = rb[q];
    }
    __syncthreads();
    if (k0 + 16 < 128) {   // prefetch next tiles; overlaps compute below
#pragma unroll
      for (int q = 0; q < 2; ++q) {
        int l = tid + q * 256;
        int m = l >> 2, kq = (l & 3) * 4;
        ra[q] = *reinterpret_cast<const float4*>(&lin[m * Ci + k0 + 16 + kq]);
        int kk = l >> 5, n4 = (l & 31) * 4;
        rb[q] = *reinterpret_cast<const float4*>(&xb[(size_t)(k0 + 16 + kk) * HW + col0 + n4]);
      }
    }
#pragma unroll
    for (int kk = 0; kk < 16; ++kk) {
      float a[8], bv[8];
      *reinterpret_cast<float4*>(&a[0]) = *reinterpret_cast<const float4*>(&As[kk][ty * 8]);
      *reinterpret_cast<float4*>(&a[4]) = *reinterpret_cast<const float4*>(&As[kk][ty * 8 + 4]);
      *reinterpret_cast<float4*>(&bv[0]) = *reinterpret_cast<const float4*>(&Bs[kk][tx * 8]);
      *reinterpret_cast<float4*>(&bv[4]) = *reinterpret_cast<const float4*>(&Bs[kk][tx * 8 + 4]);
#pragma unroll
      for (int i = 0; i < 8; i++)
#pragma unroll
        for (int j = 0; j < 8; j++) acc[i][j] += a[i] * bv[j];
    }
  }
#pragma unroll
  for (int i = 0; i < 8; i++) {
    float* yr = yb + (size_t)(ty * 8 + i) * HW + col0 + tx * 8;
    *reinterpret_cast<float4*>(yr) = make_float4(acc[i][0], acc[i][1], acc[i][2], acc[i][3]);
    *reinterpret_cast<float4*>(yr + 4) = make_float4(acc[i][4], acc[i][5], acc[i][6], acc[i][7]);
  }
}

// ---------------- small GEMM (32x32 layers): 64x64 tile, 4x4/thread (round-2) -------
__global__ __launch_bounds__(256) void gemm_kernel(
    const float* __restrict__ lin, const float* __restrict__ x,
    float* __restrict__ y, int HW) {
  const int Ci = 128;
  __shared__ __align__(16) float As[16][68];
  __shared__ __align__(16) float Bs[16][64];
  int b = blockIdx.z;
  const float* xb = x + (size_t)b * Ci * HW;
  float* yb = y + (size_t)b * CC * HW;
  int tid = threadIdx.x;
  int tx = tid & 15, ty = tid >> 4;
  int row0 = blockIdx.y * 64;
  int col0 = blockIdx.x * 64;
  float acc[4][4] = {};
  for (int k0 = 0; k0 < Ci; k0 += 16) {
    {
      int m = tid >> 2, kq = (tid & 3) * 4;
      float4 av = *reinterpret_cast<const float4*>(&lin[(row0 + m) * Ci + k0 + kq]);
      As[kq + 0][m] = av.x; As[kq + 1][m] = av.y; As[kq + 2][m] = av.z; As[kq + 3][m] = av.w;
    }
    {
      int kk = tid >> 4, n4 = (tid & 15) * 4;
      *reinterpret_cast<float4*>(&Bs[kk][n4]) =
          *reinterpret_cast<const float4*>(&xb[(size_t)(k0 + kk) * HW + col0 + n4]);
    }
    __syncthreads();
#pragma unroll
    for (int kk = 0; kk < 16; ++kk) {
      float4 a4 = *reinterpret_cast<const float4*>(&As[kk][ty * 4]);
      float4 b4 = *reinterpret_cast<const float4*>(&Bs[kk][tx * 4]);
      float a[4] = {a4.x, a4.y, a4.z, a4.w};
      float bv[4] = {b4.x, b4.y, b4.z, b4.w};
#pragma unroll
      for (int i = 0; i < 4; i++)
#pragma unroll
        for (int j = 0; j < 4; j++) acc[i][j] += a[i] * bv[j];
    }
    __syncthreads();
  }
#pragma unroll
  for (int i = 0; i < 4; i++) {
    float* yr = yb + (size_t)(row0 + ty * 4 + i) * HW + col0 + tx * 4;
    *reinterpret_cast<float4*>(yr) = make_float4(acc[i][0], acc[i][1], acc[i][2], acc[i][3]);
  }
}

// ---------------- fused sample(64x64) + MaxPool2d_G -> 32x32 ----------------------
__global__ __launch_bounds__(256) void sampmax_kernel(
    const float* __restrict__ y, const float* __restrict__ geo,
    const float* __restrict__ box, float* __restrict__ out) {
  const int H = 64, W = 64, HW = 4096;
  // sp_p: 96 rows x 64 cols, rows 0..15 & 80..95 zero, data rows 16..79.
  __shared__ __align__(16) float sp_p[96 * 64];
  // tail arena: pl (4096 floats, phases 1-2) overlapped by cb_p (64x96, phases 3-4)
  __shared__ __align__(16) float tail[64 * 96];
  __shared__ float wv[4];
  __shared__ int wi[4];
  __shared__ int am_s;
  float* pl = tail;
  float* cb_p = tail;

  int bc = blockIdx.x;
  int c = bc & (CC - 1);
  int b = bc >> 7;
  int tid = threadIdx.x;

  // phase 1: load plane + zero sp_p pad rows
  const float* plane = y + (size_t)bc * HW;
#pragma unroll
  for (int k = 0; k < 4; ++k) {
    int i4 = tid + k * 256;
    *reinterpret_cast<float4*>(&pl[i4 * 4]) = *reinterpret_cast<const float4*>(&plane[i4 * 4]);
  }
  *reinterpret_cast<float4*>(&sp_p[tid * 4]) = make_float4(0.f, 0.f, 0.f, 0.f);            // rows 0..15
  *reinterpret_cast<float4*>(&sp_p[5120 + tid * 4]) = make_float4(0.f, 0.f, 0.f, 0.f);     // rows 80..95
  __syncthreads();

  // phase 2: sample into sp_p data rows
  {
    const float* g = geo + c * 6;
    const float* bx = box + c * 6;
    float g0 = g[0], g1 = g[1], g2 = g[2], g3 = g[3], g4 = g[4], g5 = g[5];
    float b0 = bx[0], b1 = bx[1], b2 = bx[2], b3 = bx[3], b4 = bx[4], b5 = bx[5];
#pragma unroll
    for (int k = 0; k < 16; ++k) {
      int px = tid + k * 256;
      int h = px >> 6, w = px & 63;
      float xs = (2.0f * w + 1.0f) / W - 1.0f;
      float ys = (2.0f * h + 1.0f) / H - 1.0f;
      float gx = g0 * xs + g1 * ys + g2;
      float gy = g3 * xs + g4 * ys + g5;
      float ix = ((gx + 1.0f) * W - 1.0f) * 0.5f;
      float iy = ((gy + 1.0f) * H - 1.0f) * 0.5f;
      float x0 = floorf(ix), y0 = floorf(iy);
      float wx = ix - x0, wy = iy - y0;
      float v[2][2];
#pragma unroll
      for (int dy = 0; dy < 2; ++dy)
#pragma unroll
        for (int dx = 0; dx < 2; ++dx) {
          float xf = x0 + dx, yf = y0 + dy;
          bool valid = (xf >= 0.0f) && (xf <= 63.0f) && (yf >= 0.0f) && (yf <= 63.0f);
          int xi = (int)fminf(fmaxf(xf, 0.0f), 63.0f);
          int yi = (int)fminf(fmaxf(yf, 0.0f), 63.0f);
          v[dy][dx] = valid ? pl[yi * 64 + xi] : 0.0f;
        }
      float samp = (1.0f - wy) * ((1.0f - wx) * v[0][0] + wx * v[0][1]) +
                   wy * ((1.0f - wx) * v[1][0] + wx * v[1][1]);
      float bgx = b0 * xs + b1 * ys + b2;
      float bgy = b3 * xs + b4 * ys + b5;
      float bix = ((bgx + 1.0f) * W - 1.0f) * 0.5f;
      float biy = ((bgy + 1.0f) * H - 1.0f) * 0.5f;
      float bx0 = floorf(bix), by0 = floorf(biy);
      float bwx = bix - bx0, bwy = biy - by0;
      float m[2][2];
#pragma unroll
      for (int dy = 0; dy < 2; ++dy)
#pragma unroll
        for (int dx = 0; dx < 2; ++dx) {
          float xf = bx0 + dx, yf = by0 + dy;
          m[dy][dx] = ((xf >= 0.0f) && (xf <= 63.0f) && (yf >= 0.0f) && (yf <= 63.0f)) ? 1.0f : 0.0f;
        }
      float mask = (1.0f - bwy) * ((1.0f - bwx) * m[0][0] + bwx * m[0][1]) +
                   bwy * ((1.0f - bwx) * m[1][0] + bwx * m[1][1]);
      sp_p[(h + 16) * 64 + w] = samp * mask;   // pl no longer needed after this phase
    }
  }
  __syncthreads();

  // phase 3: column band sums -> cb_p (reuses pl space), 4-row strip per thread.
  // Each output h sums padded rows h..h+31 ascending (identical values to clipped sum).
  {
    int strip = tid >> 4, w4 = (tid & 15) * 4;
    int h0 = strip * 4;
    float4 a0 = make_float4(0.f, 0.f, 0.f, 0.f), a1 = a0, a2 = a0, a3 = a0;
#pragma unroll
    for (int j = 0; j < 35; ++j) {
      float4 f = *reinterpret_cast<const float4*>(&sp_p[(h0 + j) * 64 + w4]);
      if (j <= 31) { a0.x += f.x; a0.y += f.y; a0.z += f.z; a0.w += f.w; }
      if (j >= 1 && j <= 32) { a1.x += f.x; a1.y += f.y; a1.z += f.z; a1.w += f.w; }
      if (j >= 2 && j <= 33) { a2.x += f.x; a2.y += f.y; a2.z += f.z; a2.w += f.w; }
      if (j >= 3) { a3.x += f.x; a3.y += f.y; a3.z += f.z; a3.w += f.w; }
    }
    *reinterpret_cast<float4*>(&cb_p[(h0 + 0) * 96 + 16 + w4]) = a0;
    *reinterpret_cast<float4*>(&cb_p[(h0 + 1) * 96 + 16 + w4]) = a1;
    *reinterpret_cast<float4*>(&cb_p[(h0 + 2) * 96 + 16 + w4]) = a2;
    *reinterpret_cast<float4*>(&cb_p[(h0 + 3) * 96 + 16 + w4]) = a3;
    // zero cb_p pad cols (0..15 and 80..95): 64 rows x 8 float4s
#pragma unroll
    for (int q = 0; q < 2; ++q) {
      int l = tid + q * 256;
      int row = l >> 3, gq = l & 7;
      int base = row * 96 + ((gq < 4) ? gq * 4 : 80 + (gq - 4) * 4);
      *reinterpret_cast<float4*>(&cb_p[base]) = make_float4(0.f, 0.f, 0.f, 0.f);
    }
  }
  __syncthreads();

  // phase 4: row window sums + argmax (first-occurrence, partition-invariant)
  float best = -3.402823466e+38f;
  int bidx = 0x7fffffff;
#pragma unroll
  for (int k = 0; k < 4; ++k) {
    int t = tid + k * 256;
    int h = t >> 4, w4 = (t & 15) * 4;
    float f[36];
#pragma unroll
    for (int j = 0; j < 9; ++j)
      *reinterpret_cast<float4*>(&f[j * 4]) =
          *reinterpret_cast<const float4*>(&cb_p[h * 96 + w4 + 4 * j]);
#pragma unroll
    for (int d = 0; d < 4; ++d) {
      float s = 0.0f;
#pragma unroll
      for (int u = 0; u < 32; ++u) s += f[d + u];
      int i = (h << 6) + w4 + d;
      if (s > best) { best = s; bidx = i; }
    }
  }
#pragma unroll
  for (int off = 32; off > 0; off >>= 1) {
    float v2 = __shfl_down(best, off);
    int i2 = __shfl_down(bidx, off);
    if (v2 > best || (v2 == best && i2 < bidx)) { best = v2; bidx = i2; }
  }
  if ((tid & 63) == 0) { wv[tid >> 6] = best; wi[tid >> 6] = bidx; }
  __syncthreads();
  if (tid == 0) {
    float bv = wv[0]; int bi = wi[0];
#pragma unroll
    for (int k = 1; k < 4; ++k)
      if (wv[k] > bv || (wv[k] == bv && wi[k] < bi)) { bv = wv[k]; bi = wi[k]; }
    am_s = bi;
  }
  __syncthreads();

  // phase 5: 32x32 windowed gather (rows zero-padded in sp_p; cols via predicate)
  int am = am_s;
  int r = am >> 6, cx = am & 63;
  float* o = out + (size_t)bc * 1024;
  float vals[4];
#pragma unroll
  for (int d = 0; d < 4; ++d) {
    int i = tid * 4 + d;
    int oi = i >> 5, oj = i & 31;
    int rr = r + oi - 16, cj = cx + oj - 16;
    float v = 0.0f;
    if (cj >= 0 && cj < 64) v = sp_p[(rr + 16) * 64 + cj];
    vals[d] = v;
  }
  *reinterpret_cast<float4*>(&o[tid * 4]) = make_float4(vals[0], vals[1], vals[2], vals[3]);
}

// ---------------- sample (32x32) with optional fused mean-pool ----------------
template <bool POOL>
__global__ __launch_bounds__(256) void sample32_kernel(
    const float* __restrict__ y, const float* __restrict__ geo,
    const float* __restrict__ box, float* __restrict__ out,
    float* __restrict__ pooled) {
  const int H = 32, W = 32, HW = 1024;
  __shared__ __align__(16) float pl[HW];
  __shared__ float sm[256];
  int c = blockIdx.x & (CC - 1);
  int b = blockIdx.x >> 7;
  int tid = threadIdx.x;
  const float* plane = y + ((size_t)b * CC + c) * HW;
  *reinterpret_cast<float4*>(&pl[tid * 4]) = *reinterpret_cast<const float4*>(&plane[tid * 4]);
  __syncthreads();

  const float* g = geo + c * 6;
  const float* bx = box + c * 6;
  float g0 = g[0], g1 = g[1], g2 = g[2], g3 = g[3], g4 = g[4], g5 = g[5];
  float b0 = bx[0], b1 = bx[1], b2 = bx[2], b3 = bx[3], b4 = bx[4], b5 = bx[5];
  float* o = out + ((size_t)b * CC + c) * HW;
  float psum = 0.0f;

#pragma unroll
  for (int k = 0; k < 4; ++k) {
    int px = tid + k * 256;
    int h = px >> 5, w = px & 31;
    float xs = (2.0f * w + 1.0f) / W - 1.0f;
    float ys = (2.0f * h + 1.0f) / H - 1.0f;
    float gx = g0 * xs + g1 * ys + g2;
    float gy = g3 * xs + g4 * ys + g5;
    float ix = ((gx + 1.0f) * W - 1.0f) * 0.5f;
    float iy = ((gy + 1.0f) * H - 1.0f) * 0.5f;
    float x0 = floorf(ix), y0 = floorf(iy);
    float wx = ix - x0, wy = iy - y0;
    float v[2][2];
#pragma unroll
    for (int dy = 0; dy < 2; ++dy)
#pragma unroll
      for (int dx = 0; dx < 2; ++dx) {
        float xf = x0 + dx, yf = y0 + dy;
        bool valid = (xf >= 0.0f) && (xf <= 31.0f) && (yf >= 0.0f) && (yf <= 31.0f);
        int xi = (int)fminf(fmaxf(xf, 0.0f), 31.0f);
        int yi = (int)fminf(fmaxf(yf, 0.0f), 31.0f);
        v[dy][dx] = valid ? pl[yi * 32 + xi] : 0.0f;
      }
    float samp = (1.0f - wy) * ((1.0f - wx) * v[0][0] + wx * v[0][1]) +
                 wy * ((1.0f - wx) * v[1][0] + wx * v[1][1]);
    float bgx = b0 * xs + b1 * ys + b2;
    float bgy = b3 * xs + b4 * ys + b5;
    float bix = ((bgx + 1.0f) * W - 1.0f) * 0.5f;
    float biy = ((bgy + 1.0f) * H - 1.0f) * 0.5f;
    float bx0 = floorf(bix), by0 = floorf(biy);
    float bwx = bix - bx0, bwy = biy - by0;
    float m[2][2];
#pragma unroll
    for (int dy = 0; dy < 2; ++dy)
#pragma unroll
      for (int dx = 0; dx < 2; ++dx) {
        float xf = bx0 + dx, yf = by0 + dy;
        m[dy][dx] = ((xf >= 0.0f) && (xf <= 31.0f) && (yf >= 0.0f) && (yf <= 31.0f)) ? 1.0f : 0.0f;
      }
    float mask = (1.0f - bwy) * ((1.0f - bwx) * m[0][0] + bwx * m[0][1]) +
                 bwy * ((1.0f - bwx) * m[1][0] + bwx * m[1][1]);
    float res = samp * mask;
    o[px] = res;
    if (POOL) psum += res;   // same px-group order as old pool kernel (tid + 256k)
  }
  if (POOL) {
    sm[tid] = psum;
    __syncthreads();
    for (int st = 128; st > 0; st >>= 1) {
      if (tid < st) sm[tid] += sm[tid + st];
      __syncthreads();
    }
    if (tid == 0) pooled[blockIdx.x] = sm[0] * (1.0f / 1024.0f);
  }
}

// ---------------- dense head ----------------
__global__ __launch_bounds__(128) void dense_kernel(
    const float* __restrict__ pooled, const float* __restrict__ w,
    const float* __restrict__ bias, float* __restrict__ out) {
  int t = threadIdx.x;
  if (t < 80) {
    int b = t / 10, o = t % 10;
    float s = bias[o];
    const float* pb = pooled + b * 128;
    const float* wo = w + o * 128;
    for (int c = 0; c < 128; ++c) s += pb[c] * wo[c];
    out[b * 10 + o] = s;
  }
}

extern "C" void kernel_launch(void* const* d_in, const int* in_sizes, int n_in,
                              void* d_out, int out_size, void* d_ws, size_t ws_size,
                              hipStream_t stream) {
  const float* x     = (const float*)d_in[0];   // [8,3,64,64]
  const float* geo0  = (const float*)d_in[1];   // [128,2,3]
  const float* lin0  = (const float*)d_in[2];   // [128,3]
  const float* box0  = (const float*)d_in[3];   // [128,2,3]
  const float* geos  = (const float*)d_in[4];   // [3,128,2,3]
  const float* lins  = (const float*)d_in[5];   // [3,128,128]
  const float* boxes = (const float*)d_in[6];   // [3,128,2,3]
  const float* dw    = (const float*)d_in[7];   // [10,128]
  const float* db    = (const float*)d_in[8];   // [10]

  float* out  = (float*)d_out;      // [8,10] then feat [8,128,32,32]
  float* feat = out + 80;
  float* ws   = (float*)d_ws;
  float* ws0  = ws;                 // 16 MB
  float* ws1  = ws + 4194304;       // 16 MB
  float* pooled = ws + 8388608;     // 1024 floats

  // inLay: fused combine(Ci=3) + sample -> ws1
  inlay_sample_kernel<<<dim3(16, CC, BB), 256, 0, stream>>>(x, lin0, geo0, box0, ws1);
  // layer 0: combine (128x128 tile GEMM) -> fused sample+maxpool -> [8,128,32,32]
  gemm128_kernel<<<dim3(32, 1, BB), 256, 0, stream>>>(lins, ws1, ws0, 4096);
  sampmax_kernel<<<dim3(BB * CC), 256, 0, stream>>>(ws0, geos, boxes, ws1);
  // layer 2: combine -> sample (32x32)
  gemm_kernel<<<dim3(16, 2, BB), 256, 0, stream>>>(lins + 16384, ws1, ws0, 1024);
  sample32_kernel<false><<<dim3(BB * CC), 256, 0, stream>>>(ws0, geos + 768, boxes + 768, ws1, nullptr);
  // layer 3: combine -> sample (32x32) + fused mean-pool, feat straight to d_out
  gemm_kernel<<<dim3(16, 2, BB), 256, 0, stream>>>(lins + 32768, ws1, ws0, 1024);
  sample32_kernel<true><<<dim3(BB * CC), 256, 0, stream>>>(ws0, geos + 1536, boxes + 1536, feat, pooled);
  // head
  dense_kernel<<<1, 128, 0, stream>>>(pooled, dw, db, out);
}

// Round 4
// 179.621 us; speedup vs baseline: 1.4277x; 1.0371x over previous
//
#include <hip/hip_runtime.h>

#define BB 8
#define CC 128

// ---------------- fused inLay: LDS-staged 3 planes + combine + sample + box mask ----
__global__ __launch_bounds__(256) void inlay_sample_kernel(
    const float* __restrict__ x, const float* __restrict__ lin,
    const float* __restrict__ geo, const float* __restrict__ box,
    float* __restrict__ out) {
  const int H = 64, W = 64, HW = 4096;
  __shared__ __align__(16) float xpl[3 * 4096];   // 48 KB
  int bc = blockIdx.x;
  int c = bc & (CC - 1);
  int b = bc >> 7;
  int tid = threadIdx.x;
  const float* xb = x + (size_t)b * 3 * HW;
#pragma unroll
  for (int q = 0; q < 12; ++q) {
    int i4 = tid + q * 256;
    *reinterpret_cast<float4*>(&xpl[i4 * 4]) = *reinterpret_cast<const float4*>(&xb[i4 * 4]);
  }
  __syncthreads();

  float w0 = lin[c * 3 + 0], w1 = lin[c * 3 + 1], w2 = lin[c * 3 + 2];
  const float* g = geo + c * 6;
  const float* bx = box + c * 6;
  float g0 = g[0], g1 = g[1], g2 = g[2], g3 = g[3], g4 = g[4], g5 = g[5];
  float b0 = bx[0], b1 = bx[1], b2 = bx[2], b3 = bx[3], b4 = bx[4], b5 = bx[5];
  float* o = out + ((size_t)b * CC + c) * HW;

#pragma unroll
  for (int k = 0; k < 16; ++k) {
    int px = tid + k * 256;
    int h = px >> 6, w = px & 63;
    float xs = (2.0f * w + 1.0f) / W - 1.0f;
    float ys = (2.0f * h + 1.0f) / H - 1.0f;
    float gx = g0 * xs + g1 * ys + g2;
    float gy = g3 * xs + g4 * ys + g5;
    float ix = ((gx + 1.0f) * W - 1.0f) * 0.5f;
    float iy = ((gy + 1.0f) * H - 1.0f) * 0.5f;
    float x0 = floorf(ix), y0 = floorf(iy);
    float wx = ix - x0, wy = iy - y0;
    float v[2][2];
#pragma unroll
    for (int dy = 0; dy < 2; ++dy)
#pragma unroll
      for (int dx = 0; dx < 2; ++dx) {
        float xf = x0 + dx, yf = y0 + dy;
        bool valid = (xf >= 0.0f) && (xf <= 63.0f) && (yf >= 0.0f) && (yf <= 63.0f);
        int xi = (int)fminf(fmaxf(xf, 0.0f), 63.0f);
        int yi = (int)fminf(fmaxf(yf, 0.0f), 63.0f);
        int t = yi * 64 + xi;
        float vv = w0 * xpl[t] + w1 * xpl[4096 + t] + w2 * xpl[8192 + t];
        v[dy][dx] = valid ? vv : 0.0f;
      }
    float samp = (1.0f - wy) * ((1.0f - wx) * v[0][0] + wx * v[0][1]) +
                 wy * ((1.0f - wx) * v[1][0] + wx * v[1][1]);

    float bgx = b0 * xs + b1 * ys + b2;
    float bgy = b3 * xs + b4 * ys + b5;
    float bix = ((bgx + 1.0f) * W - 1.0f) * 0.5f;
    float biy = ((bgy + 1.0f) * H - 1.0f) * 0.5f;
    float bx0 = floorf(bix), by0 = floorf(biy);
    float bwx = bix - bx0, bwy = biy - by0;
    float m[2][2];
#pragma unroll
    for (int dy = 0; dy < 2; ++dy)
#pragma unroll
      for (int dx = 0; dx < 2; ++dx) {
        float xf = bx0 + dx, yf = by0 + dy;
        m[dy][dx] = ((xf >= 0.0f) && (xf <= 63.0f) && (yf >= 0.0f) && (yf <= 63.0f)) ? 1.0f : 0.0f;
      }
    float mask = (1.0f - bwy) * ((1.0f - bwx) * m[0][0] + bwx * m[0][1]) +
                 bwy * ((1.0f - bwx) * m[1][0] + bwx * m[1][1]);
    o[px] = samp * mask;
  }
}

// ---------------- layer-0 GEMM: 64x64 tile, 4x4/thread, register prefetch ----------
__global__ __launch_bounds__(256) void gemm64_kernel(
    const float* __restrict__ lin, const float* __restrict__ x,
    float* __restrict__ y, int HW) {
  const int Ci = 128;
  __shared__ __align__(16) float As[16][68];
  __shared__ __align__(16) float Bs[16][64];
  int b = blockIdx.z;
  const float* xb = x + (size_t)b * Ci * HW;
  float* yb = y + (size_t)b * CC * HW;
  int tid = threadIdx.x;
  int tx = tid & 15, ty = tid >> 4;
  int row0 = blockIdx.y * 64;
  int col0 = blockIdx.x * 64;
  int m = tid >> 2, kq = (tid & 3) * 4;
  int kk = tid >> 4, n4 = (tid & 15) * 4;
  float acc[4][4] = {};
  float4 ra = *reinterpret_cast<const float4*>(&lin[(row0 + m) * Ci + kq]);
  float4 rb = *reinterpret_cast<const float4*>(&xb[(size_t)kk * HW + col0 + n4]);
  for (int k0 = 0; k0 < 128; k0 += 16) {
    __syncthreads();
    As[kq + 0][m] = ra.x; As[kq + 1][m] = ra.y; As[kq + 2][m] = ra.z; As[kq + 3][m] = ra.w;
    *reinterpret_cast<float4*>(&Bs[kk][n4]) = rb;
    __syncthreads();
    if (k0 + 16 < 128) {
      ra = *reinterpret_cast<const float4*>(&lin[(row0 + m) * Ci + k0 + 16 + kq]);
      rb = *reinterpret_cast<const float4*>(&xb[(size_t)(k0 + 16 + kk) * HW + col0 + n4]);
    }
#pragma unroll
    for (int kki = 0; kki < 16; ++kki) {
      float4 a4 = *reinterpret_cast<const float4*>(&As[kki][ty * 4]);
      float4 b4 = *reinterpret_cast<const float4*>(&Bs[kki][tx * 4]);
      float a[4] = {a4.x, a4.y, a4.z, a4.w};
      float bv[4] = {b4.x, b4.y, b4.z, b4.w};
#pragma unroll
      for (int i = 0; i < 4; i++)
#pragma unroll
        for (int j = 0; j < 4; j++) acc[i][j] += a[i] * bv[j];
    }
  }
#pragma unroll
  for (int i = 0; i < 4; i++) {
    float* yr = yb + (size_t)(row0 + ty * 4 + i) * HW + col0 + tx * 4;
    *reinterpret_cast<float4*>(yr) = make_float4(acc[i][0], acc[i][1], acc[i][2], acc[i][3]);
  }
}

// ---------------- fused sample(64x64) + MaxPool2d_G -> 32x32 ----------------------
__global__ __launch_bounds__(256) void sampmax_kernel(
    const float* __restrict__ y, const float* __restrict__ geo,
    const float* __restrict__ box, float* __restrict__ out) {
  const int H = 64, W = 64, HW = 4096;
  __shared__ __align__(16) float sp_p[96 * 64];
  __shared__ __align__(16) float tail[64 * 96];
  __shared__ float wv[4];
  __shared__ int wi[4];
  __shared__ int am_s;
  float* pl = tail;
  float* cb_p = tail;

  int bc = blockIdx.x;
  int c = bc & (CC - 1);
  int b = bc >> 7;
  int tid = threadIdx.x;

  const float* plane = y + (size_t)bc * HW;
#pragma unroll
  for (int k = 0; k < 4; ++k) {
    int i4 = tid + k * 256;
    *reinterpret_cast<float4*>(&pl[i4 * 4]) = *reinterpret_cast<const float4*>(&plane[i4 * 4]);
  }
  *reinterpret_cast<float4*>(&sp_p[tid * 4]) = make_float4(0.f, 0.f, 0.f, 0.f);
  *reinterpret_cast<float4*>(&sp_p[5120 + tid * 4]) = make_float4(0.f, 0.f, 0.f, 0.f);
  __syncthreads();

  {
    const float* g = geo + c * 6;
    const float* bx = box + c * 6;
    float g0 = g[0], g1 = g[1], g2 = g[2], g3 = g[3], g4 = g[4], g5 = g[5];
    float b0 = bx[0], b1 = bx[1], b2 = bx[2], b3 = bx[3], b4 = bx[4], b5 = bx[5];
#pragma unroll
    for (int k = 0; k < 16; ++k) {
      int px = tid + k * 256;
      int h = px >> 6, w = px & 63;
      float xs = (2.0f * w + 1.0f) / W - 1.0f;
      float ys = (2.0f * h + 1.0f) / H - 1.0f;
      float gx = g0 * xs + g1 * ys + g2;
      float gy = g3 * xs + g4 * ys + g5;
      float ix = ((gx + 1.0f) * W - 1.0f) * 0.5f;
      float iy = ((gy + 1.0f) * H - 1.0f) * 0.5f;
      float x0 = floorf(ix), y0 = floorf(iy);
      float wx = ix - x0, wy = iy - y0;
      float v[2][2];
#pragma unroll
      for (int dy = 0; dy < 2; ++dy)
#pragma unroll
        for (int dx = 0; dx < 2; ++dx) {
          float xf = x0 + dx, yf = y0 + dy;
          bool valid = (xf >= 0.0f) && (xf <= 63.0f) && (yf >= 0.0f) && (yf <= 63.0f);
          int xi = (int)fminf(fmaxf(xf, 0.0f), 63.0f);
          int yi = (int)fminf(fmaxf(yf, 0.0f), 63.0f);
          v[dy][dx] = valid ? pl[yi * 64 + xi] : 0.0f;
        }
      float samp = (1.0f - wy) * ((1.0f - wx) * v[0][0] + wx * v[0][1]) +
                   wy * ((1.0f - wx) * v[1][0] + wx * v[1][1]);
      float bgx = b0 * xs + b1 * ys + b2;
      float bgy = b3 * xs + b4 * ys + b5;
      float bix = ((bgx + 1.0f) * W - 1.0f) * 0.5f;
      float biy = ((bgy + 1.0f) * H - 1.0f) * 0.5f;
      float bx0 = floorf(bix), by0 = floorf(biy);
      float bwx = bix - bx0, bwy = biy - by0;
      float m[2][2];
#pragma unroll
      for (int dy = 0; dy < 2; ++dy)
#pragma unroll
        for (int dx = 0; dx < 2; ++dx) {
          float xf = bx0 + dx, yf = by0 + dy;
          m[dy][dx] = ((xf >= 0.0f) && (xf <= 63.0f) && (yf >= 0.0f) && (yf <= 63.0f)) ? 1.0f : 0.0f;
        }
      float mask = (1.0f - bwy) * ((1.0f - bwx) * m[0][0] + bwx * m[0][1]) +
                   bwy * ((1.0f - bwx) * m[1][0] + bwx * m[1][1]);
      sp_p[(h + 16) * 64 + w] = samp * mask;
    }
  }
  __syncthreads();

  {
    int strip = tid >> 4, w4 = (tid & 15) * 4;
    int h0 = strip * 4;
    float4 a0 = make_float4(0.f, 0.f, 0.f, 0.f), a1 = a0, a2 = a0, a3 = a0;
#pragma unroll
    for (int j = 0; j < 35; ++j) {
      float4 f = *reinterpret_cast<const float4*>(&sp_p[(h0 + j) * 64 + w4]);
      if (j <= 31) { a0.x += f.x; a0.y += f.y; a0.z += f.z; a0.w += f.w; }
      if (j >= 1 && j <= 32) { a1.x += f.x; a1.y += f.y; a1.z += f.z; a1.w += f.w; }
      if (j >= 2 && j <= 33) { a2.x += f.x; a2.y += f.y; a2.z += f.z; a2.w += f.w; }
      if (j >= 3) { a3.x += f.x; a3.y += f.y; a3.z += f.z; a3.w += f.w; }
    }
    *reinterpret_cast<float4*>(&cb_p[(h0 + 0) * 96 + 16 + w4]) = a0;
    *reinterpret_cast<float4*>(&cb_p[(h0 + 1) * 96 + 16 + w4]) = a1;
    *reinterpret_cast<float4*>(&cb_p[(h0 + 2) * 96 + 16 + w4]) = a2;
    *reinterpret_cast<float4*>(&cb_p[(h0 + 3) * 96 + 16 + w4]) = a3;
#pragma unroll
    for (int q = 0; q < 2; ++q) {
      int l = tid + q * 256;
      int row = l >> 3, gq = l & 7;
      int base = row * 96 + ((gq < 4) ? gq * 4 : 80 + (gq - 4) * 4);
      *reinterpret_cast<float4*>(&cb_p[base]) = make_float4(0.f, 0.f, 0.f, 0.f);
    }
  }
  __syncthreads();

  float best = -3.402823466e+38f;
  int bidx = 0x7fffffff;
#pragma unroll
  for (int k = 0; k < 4; ++k) {
    int t = tid + k * 256;
    int h = t >> 4, w4 = (t & 15) * 4;
    float f[36];
#pragma unroll
    for (int j = 0; j < 9; ++j)
      *reinterpret_cast<float4*>(&f[j * 4]) =
          *reinterpret_cast<const float4*>(&cb_p[h * 96 + w4 + 4 * j]);
#pragma unroll
    for (int d = 0; d < 4; ++d) {
      float s = 0.0f;
#pragma unroll
      for (int u = 0; u < 32; ++u) s += f[d + u];
      int i = (h << 6) + w4 + d;
      if (s > best) { best = s; bidx = i; }
    }
  }
#pragma unroll
  for (int off = 32; off > 0; off >>= 1) {
    float v2 = __shfl_down(best, off);
    int i2 = __shfl_down(bidx, off);
    if (v2 > best || (v2 == best && i2 < bidx)) { best = v2; bidx = i2; }
  }
  if ((tid & 63) == 0) { wv[tid >> 6] = best; wi[tid >> 6] = bidx; }
  __syncthreads();
  if (tid == 0) {
    float bv = wv[0]; int bi = wi[0];
#pragma unroll
    for (int k = 1; k < 4; ++k)
      if (wv[k] > bv || (wv[k] == bv && wi[k] < bi)) { bv = wv[k]; bi = wi[k]; }
    am_s = bi;
  }
  __syncthreads();

  int am = am_s;
  int r = am >> 6, cx = am & 63;
  float* o = out + (size_t)bc * 1024;
  float vals[4];
#pragma unroll
  for (int d = 0; d < 4; ++d) {
    int i = tid * 4 + d;
    int oi = i >> 5, oj = i & 31;
    int rr = r + oi - 16, cj = cx + oj - 16;
    float v = 0.0f;
    if (cj >= 0 && cj < 64) v = sp_p[(rr + 16) * 64 + cj];
    vals[d] = v;
  }
  *reinterpret_cast<float4*>(&o[tid * 4]) = make_float4(vals[0], vals[1], vals[2], vals[3]);
}

// ---------------- fused 32x32 layer: GEMM (4 ch/block) + sample + optional pool ----
template <bool POOL>
__global__ __launch_bounds__(256) void fused32_kernel(
    const float* __restrict__ lin, const float* __restrict__ x,
    const float* __restrict__ geo, const float* __restrict__ box,
    float* __restrict__ out, float* __restrict__ pooled) {
  const int H = 32, W = 32, HW = 1024;
  __shared__ __align__(16) float pls[4][1024];
  __shared__ float wred[16];
  int b = blockIdx.x >> 5;
  int c0 = (blockIdx.x & 31) * 4;
  int tid = threadIdx.x;
  const float* xb = x + (size_t)b * 128 * HW;
  const float* l0 = lin + (c0 + 0) * 128;
  const float* l1 = lin + (c0 + 1) * 128;
  const float* l2 = lin + (c0 + 2) * 128;
  const float* l3 = lin + (c0 + 3) * 128;
  int px4 = tid * 4;

  float4 acc0 = make_float4(0.f, 0.f, 0.f, 0.f);
  float4 acc1 = acc0, acc2 = acc0, acc3 = acc0;
#pragma unroll 8
  for (int k = 0; k < 128; ++k) {
    float4 xv = *reinterpret_cast<const float4*>(&xb[(size_t)k * HW + px4]);
    float s0 = l0[k], s1 = l1[k], s2 = l2[k], s3 = l3[k];   // block-uniform -> s_load
    acc0.x += s0 * xv.x; acc0.y += s0 * xv.y; acc0.z += s0 * xv.z; acc0.w += s0 * xv.w;
    acc1.x += s1 * xv.x; acc1.y += s1 * xv.y; acc1.z += s1 * xv.z; acc1.w += s1 * xv.w;
    acc2.x += s2 * xv.x; acc2.y += s2 * xv.y; acc2.z += s2 * xv.z; acc2.w += s2 * xv.w;
    acc3.x += s3 * xv.x; acc3.y += s3 * xv.y; acc3.z += s3 * xv.z; acc3.w += s3 * xv.w;
  }
  *reinterpret_cast<float4*>(&pls[0][px4]) = acc0;
  *reinterpret_cast<float4*>(&pls[1][px4]) = acc1;
  *reinterpret_cast<float4*>(&pls[2][px4]) = acc2;
  *reinterpret_cast<float4*>(&pls[3][px4]) = acc3;
  __syncthreads();

  float psum[4] = {0.f, 0.f, 0.f, 0.f};
#pragma unroll
  for (int c = 0; c < 4; ++c) {
    const float* g = geo + (c0 + c) * 6;
    const float* bxp = box + (c0 + c) * 6;
    float g0 = g[0], g1 = g[1], g2 = g[2], g3 = g[3], g4 = g[4], g5 = g[5];
    float b0 = bxp[0], b1 = bxp[1], b2 = bxp[2], b3 = bxp[3], b4 = bxp[4], b5 = bxp[5];
    float* o = out + ((size_t)b * CC + c0 + c) * HW;
    const float* pl = pls[c];
#pragma unroll
    for (int k = 0; k < 4; ++k) {
      int px = tid + k * 256;
      int h = px >> 5, w = px & 31;
      float xs = (2.0f * w + 1.0f) / W - 1.0f;
      float ys = (2.0f * h + 1.0f) / H - 1.0f;
      float gx = g0 * xs + g1 * ys + g2;
      float gy = g3 * xs + g4 * ys + g5;
      float ix = ((gx + 1.0f) * W - 1.0f) * 0.5f;
      float iy = ((gy + 1.0f) * H - 1.0f) * 0.5f;
      float x0 = floorf(ix), y0 = floorf(iy);
      float wx = ix - x0, wy = iy - y0;
      float v[2][2];
#pragma unroll
      for (int dy = 0; dy < 2; ++dy)
#pragma unroll
        for (int dx = 0; dx < 2; ++dx) {
          float xf = x0 + dx, yf = y0 + dy;
          bool valid = (xf >= 0.0f) && (xf <= 31.0f) && (yf >= 0.0f) && (yf <= 31.0f);
          int xi = (int)fminf(fmaxf(xf, 0.0f), 31.0f);
          int yi = (int)fminf(fmaxf(yf, 0.0f), 31.0f);
          v[dy][dx] = valid ? pl[yi * 32 + xi] : 0.0f;
        }
      float samp = (1.0f - wy) * ((1.0f - wx) * v[0][0] + wx * v[0][1]) +
                   wy * ((1.0f - wx) * v[1][0] + wx * v[1][1]);
      float bgx = b0 * xs + b1 * ys + b2;
      float bgy = b3 * xs + b4 * ys + b5;
      float bix = ((bgx + 1.0f) * W - 1.0f) * 0.5f;
      float biy = ((bgy + 1.0f) * H - 1.0f) * 0.5f;
      float bx0 = floorf(bix), by0 = floorf(biy);
      float bwx = bix - bx0, bwy = biy - by0;
      float m[2][2];
#pragma unroll
      for (int dy = 0; dy < 2; ++dy)
#pragma unroll
        for (int dx = 0; dx < 2; ++dx) {
          float xf = bx0 + dx, yf = by0 + dy;
          m[dy][dx] = ((xf >= 0.0f) && (xf <= 31.0f) && (yf >= 0.0f) && (yf <= 31.0f)) ? 1.0f : 0.0f;
        }
      float mask = (1.0f - bwy) * ((1.0f - bwx) * m[0][0] + bwx * m[0][1]) +
                   bwy * ((1.0f - bwx) * m[1][0] + bwx * m[1][1]);
      float res = samp * mask;
      o[px] = res;
      if (POOL) psum[c] += res;
    }
  }
  if (POOL) {
    int lane = tid & 63, wid = tid >> 6;
#pragma unroll
    for (int c = 0; c < 4; ++c) {
      float r = psum[c];
#pragma unroll
      for (int off = 32; off > 0; off >>= 1) r += __shfl_down(r, off);
      if (lane == 0) wred[c * 4 + wid] = r;
    }
    __syncthreads();
    if (tid < 4) {
      float t = wred[tid * 4] + wred[tid * 4 + 1] + wred[tid * 4 + 2] + wred[tid * 4 + 3];
      pooled[b * CC + c0 + tid] = t * (1.0f / 1024.0f);
    }
  }
}

// ---------------- dense head ----------------
__global__ __launch_bounds__(128) void dense_kernel(
    const float* __restrict__ pooled, const float* __restrict__ w,
    const float* __restrict__ bias, float* __restrict__ out) {
  int t = threadIdx.x;
  if (t < 80) {
    int b = t / 10, o = t % 10;
    float s = bias[o];
    const float* pb = pooled + b * 128;
    const float* wo = w + o * 128;
    for (int c = 0; c < 128; ++c) s += pb[c] * wo[c];
    out[b * 10 + o] = s;
  }
}

extern "C" void kernel_launch(void* const* d_in, const int* in_sizes, int n_in,
                              void* d_out, int out_size, void* d_ws, size_t ws_size,
                              hipStream_t stream) {
  const float* x     = (const float*)d_in[0];   // [8,3,64,64]
  const float* geo0  = (const float*)d_in[1];   // [128,2,3]
  const float* lin0  = (const float*)d_in[2];   // [128,3]
  const float* box0  = (const float*)d_in[3];   // [128,2,3]
  const float* geos  = (const float*)d_in[4];   // [3,128,2,3]
  const float* lins  = (const float*)d_in[5];   // [3,128,128]
  const float* boxes = (const float*)d_in[6];   // [3,128,2,3]
  const float* dw    = (const float*)d_in[7];   // [10,128]
  const float* db    = (const float*)d_in[8];   // [10]

  float* out  = (float*)d_out;      // [8,10] then feat [8,128,32,32]
  float* feat = out + 80;
  float* ws   = (float*)d_ws;
  float* ws0  = ws;                 // 16 MB
  float* ws1  = ws + 4194304;       // 16 MB
  float* pooled = ws + 8388608;     // 1024 floats

  // inLay: fused combine(Ci=3) + sample -> ws1
  inlay_sample_kernel<<<dim3(BB * CC), 256, 0, stream>>>(x, lin0, geo0, box0, ws1);
  // layer 0: combine (64x64 tiles, 4 blocks/CU) -> fused sample+maxpool -> 32x32
  gemm64_kernel<<<dim3(64, 2, BB), 256, 0, stream>>>(lins, ws1, ws0, 4096);
  sampmax_kernel<<<dim3(BB * CC), 256, 0, stream>>>(ws0, geos, boxes, ws1);
  // layer 2: fused GEMM + sample
  fused32_kernel<false><<<dim3(256), 256, 0, stream>>>(lins + 16384, ws1, geos + 768, boxes + 768, ws0, nullptr);
  // layer 3: fused GEMM + sample + mean-pool, feat straight to d_out
  fused32_kernel<true><<<dim3(256), 256, 0, stream>>>(lins + 32768, ws0, geos + 1536, boxes + 1536, feat, pooled);
  // head
  dense_kernel<<<1, 128, 0, stream>>>(pooled, dw, db, out);
}

// Round 5
// 178.840 us; speedup vs baseline: 1.4339x; 1.0044x over previous
//
#include <hip/hip_runtime.h>

#define BB 8
#define CC 128

// ---------------- fused inLay: LDS-staged 3 planes + combine + sample + box mask ----
__global__ __launch_bounds__(256) void inlay_sample_kernel(
    const float* __restrict__ x, const float* __restrict__ lin,
    const float* __restrict__ geo, const float* __restrict__ box,
    float* __restrict__ out) {
  const int H = 64, W = 64, HW = 4096;
  __shared__ __align__(16) float xpl[3 * 4096];   // 48 KB
  int bc = blockIdx.x;
  int c = bc & (CC - 1);
  int b = bc >> 7;
  int tid = threadIdx.x;
  const float* xb = x + (size_t)b * 3 * HW;
#pragma unroll
  for (int q = 0; q < 12; ++q) {
    int i4 = tid + q * 256;
    *reinterpret_cast<float4*>(&xpl[i4 * 4]) = *reinterpret_cast<const float4*>(&xb[i4 * 4]);
  }
  __syncthreads();

  float w0 = lin[c * 3 + 0], w1 = lin[c * 3 + 1], w2 = lin[c * 3 + 2];
  const float* g = geo + c * 6;
  const float* bx = box + c * 6;
  float g0 = g[0], g1 = g[1], g2 = g[2], g3 = g[3], g4 = g[4], g5 = g[5];
  float b0 = bx[0], b1 = bx[1], b2 = bx[2], b3 = bx[3], b4 = bx[4], b5 = bx[5];
  float* o = out + ((size_t)b * CC + c) * HW;

#pragma unroll
  for (int k = 0; k < 16; ++k) {
    int px = tid + k * 256;
    int h = px >> 6, w = px & 63;
    float xs = (2.0f * w + 1.0f) / W - 1.0f;
    float ys = (2.0f * h + 1.0f) / H - 1.0f;
    float gx = g0 * xs + g1 * ys + g2;
    float gy = g3 * xs + g4 * ys + g5;
    float ix = ((gx + 1.0f) * W - 1.0f) * 0.5f;
    float iy = ((gy + 1.0f) * H - 1.0f) * 0.5f;
    float x0 = floorf(ix), y0 = floorf(iy);
    float wx = ix - x0, wy = iy - y0;
    float v[2][2];
#pragma unroll
    for (int dy = 0; dy < 2; ++dy)
#pragma unroll
      for (int dx = 0; dx < 2; ++dx) {
        float xf = x0 + dx, yf = y0 + dy;
        bool valid = (xf >= 0.0f) && (xf <= 63.0f) && (yf >= 0.0f) && (yf <= 63.0f);
        int xi = (int)fminf(fmaxf(xf, 0.0f), 63.0f);
        int yi = (int)fminf(fmaxf(yf, 0.0f), 63.0f);
        int t = yi * 64 + xi;
        float vv = w0 * xpl[t] + w1 * xpl[4096 + t] + w2 * xpl[8192 + t];
        v[dy][dx] = valid ? vv : 0.0f;
      }
    float samp = (1.0f - wy) * ((1.0f - wx) * v[0][0] + wx * v[0][1]) +
                 wy * ((1.0f - wx) * v[1][0] + wx * v[1][1]);

    float bgx = b0 * xs + b1 * ys + b2;
    float bgy = b3 * xs + b4 * ys + b5;
    float bix = ((bgx + 1.0f) * W - 1.0f) * 0.5f;
    float biy = ((bgy + 1.0f) * H - 1.0f) * 0.5f;
    float bx0 = floorf(bix), by0 = floorf(biy);
    float bwx = bix - bx0, bwy = biy - by0;
    float m[2][2];
#pragma unroll
    for (int dy = 0; dy < 2; ++dy)
#pragma unroll
      for (int dx = 0; dx < 2; ++dx) {
        float xf = bx0 + dx, yf = by0 + dy;
        m[dy][dx] = ((xf >= 0.0f) && (xf <= 63.0f) && (yf >= 0.0f) && (yf <= 63.0f)) ? 1.0f : 0.0f;
      }
    float mask = (1.0f - bwy) * ((1.0f - bwx) * m[0][0] + bwx * m[0][1]) +
                 bwy * ((1.0f - bwx) * m[1][0] + bwx * m[1][1]);
    o[px] = samp * mask;
  }
}

// ---------------- layer-0 GEMM: 64x64 tile, 4x4/thread, register prefetch ----------
__global__ __launch_bounds__(256) void gemm64_kernel(
    const float* __restrict__ lin, const float* __restrict__ x,
    float* __restrict__ y, int HW) {
  const int Ci = 128;
  __shared__ __align__(16) float As[16][68];
  __shared__ __align__(16) float Bs[16][64];
  int b = blockIdx.z;
  const float* xb = x + (size_t)b * Ci * HW;
  float* yb = y + (size_t)b * CC * HW;
  int tid = threadIdx.x;
  int tx = tid & 15, ty = tid >> 4;
  int row0 = blockIdx.y * 64;
  int col0 = blockIdx.x * 64;
  int m = tid >> 2, kq = (tid & 3) * 4;
  int kk = tid >> 4, n4 = (tid & 15) * 4;
  float acc[4][4] = {};
  float4 ra = *reinterpret_cast<const float4*>(&lin[(row0 + m) * Ci + kq]);
  float4 rb = *reinterpret_cast<const float4*>(&xb[(size_t)kk * HW + col0 + n4]);
  for (int k0 = 0; k0 < 128; k0 += 16) {
    __syncthreads();
    As[kq + 0][m] = ra.x; As[kq + 1][m] = ra.y; As[kq + 2][m] = ra.z; As[kq + 3][m] = ra.w;
    *reinterpret_cast<float4*>(&Bs[kk][n4]) = rb;
    __syncthreads();
    if (k0 + 16 < 128) {
      ra = *reinterpret_cast<const float4*>(&lin[(row0 + m) * Ci + k0 + 16 + kq]);
      rb = *reinterpret_cast<const float4*>(&xb[(size_t)(k0 + 16 + kk) * HW + col0 + n4]);
    }
#pragma unroll
    for (int kki = 0; kki < 16; ++kki) {
      float4 a4 = *reinterpret_cast<const float4*>(&As[kki][ty * 4]);
      float4 b4 = *reinterpret_cast<const float4*>(&Bs[kki][tx * 4]);
      float a[4] = {a4.x, a4.y, a4.z, a4.w};
      float bv[4] = {b4.x, b4.y, b4.z, b4.w};
#pragma unroll
      for (int i = 0; i < 4; i++)
#pragma unroll
        for (int j = 0; j < 4; j++) acc[i][j] += a[i] * bv[j];
    }
  }
#pragma unroll
  for (int i = 0; i < 4; i++) {
    float* yr = yb + (size_t)(row0 + ty * 4 + i) * HW + col0 + tx * 4;
    *reinterpret_cast<float4*>(yr) = make_float4(acc[i][0], acc[i][1], acc[i][2], acc[i][3]);
  }
}

// ---------------- fused sample(64x64) + MaxPool2d_G -> 32x32, 1024 threads ---------
// Strides: sp 68 (rows 16 banks apart for 4-row strips), cb 100. All sums keep the
// exact term sequence of the round-4 version (zeros added explicitly) -> bit-identical.
__global__ __launch_bounds__(1024, 8) void sampmax_kernel(
    const float* __restrict__ y, const float* __restrict__ geo,
    const float* __restrict__ box, float* __restrict__ out) {
  __shared__ __align__(16) float sp[64 * 68];      // sampled plane, padded stride
  __shared__ __align__(16) float arena[64 * 100];  // pl (ph1-2) then cb (ph3-4)
  __shared__ float wv[16];
  __shared__ int wi[16];
  __shared__ int am_s;
  float* pl = arena;
  float* cb = arena;

  int bc = blockIdx.x;
  int c = bc & (CC - 1);
  int b = bc >> 7;
  int tid = threadIdx.x;

  // phase 1: load plane (contiguous 64-wide layout)
  const float* plane = y + (size_t)bc * 4096;
  *reinterpret_cast<float4*>(&pl[tid * 4]) = *reinterpret_cast<const float4*>(&plane[tid * 4]);
  __syncthreads();

  // phase 2: sample 4 px/thread -> sp
  {
    const float* g = geo + c * 6;
    const float* bx = box + c * 6;
    float g0 = g[0], g1 = g[1], g2 = g[2], g3 = g[3], g4 = g[4], g5 = g[5];
    float b0 = bx[0], b1 = bx[1], b2 = bx[2], b3 = bx[3], b4 = bx[4], b5 = bx[5];
#pragma unroll
    for (int k = 0; k < 4; ++k) {
      int px = tid + k * 1024;
      int h = px >> 6, w = px & 63;
      float xs = (2.0f * w + 1.0f) / 64.0f - 1.0f;
      float ys = (2.0f * h + 1.0f) / 64.0f - 1.0f;
      float gx = g0 * xs + g1 * ys + g2;
      float gy = g3 * xs + g4 * ys + g5;
      float ix = ((gx + 1.0f) * 64.0f - 1.0f) * 0.5f;
      float iy = ((gy + 1.0f) * 64.0f - 1.0f) * 0.5f;
      float x0 = floorf(ix), y0 = floorf(iy);
      float wx = ix - x0, wy = iy - y0;
      float v[2][2];
#pragma unroll
      for (int dy = 0; dy < 2; ++dy)
#pragma unroll
        for (int dx = 0; dx < 2; ++dx) {
          float xf = x0 + dx, yf = y0 + dy;
          bool valid = (xf >= 0.0f) && (xf <= 63.0f) && (yf >= 0.0f) && (yf <= 63.0f);
          int xi = (int)fminf(fmaxf(xf, 0.0f), 63.0f);
          int yi = (int)fminf(fmaxf(yf, 0.0f), 63.0f);
          v[dy][dx] = valid ? pl[yi * 64 + xi] : 0.0f;
        }
      float samp = (1.0f - wy) * ((1.0f - wx) * v[0][0] + wx * v[0][1]) +
                   wy * ((1.0f - wx) * v[1][0] + wx * v[1][1]);
      float bgx = b0 * xs + b1 * ys + b2;
      float bgy = b3 * xs + b4 * ys + b5;
      float bix = ((bgx + 1.0f) * 64.0f - 1.0f) * 0.5f;
      float biy = ((bgy + 1.0f) * 64.0f - 1.0f) * 0.5f;
      float bx0 = floorf(bix), by0 = floorf(biy);
      float bwx = bix - bx0, bwy = biy - by0;
      float m[2][2];
#pragma unroll
      for (int dy = 0; dy < 2; ++dy)
#pragma unroll
        for (int dx = 0; dx < 2; ++dx) {
          float xf = bx0 + dx, yf = by0 + dy;
          m[dy][dx] = ((xf >= 0.0f) && (xf <= 63.0f) && (yf >= 0.0f) && (yf <= 63.0f)) ? 1.0f : 0.0f;
        }
      float mask = (1.0f - bwy) * ((1.0f - bwx) * m[0][0] + bwx * m[0][1]) +
                   bwy * ((1.0f - bwx) * m[1][0] + bwx * m[1][1]);
      sp[h * 68 + w] = samp * mask;
    }
  }
  __syncthreads();   // pl dead; cb (same arena) written next

  // phase 3: column band sums. strips of 4 output rows (threads 0..255);
  // threads 256..767 zero cb's side pads. Row clip via masked exact-0 adds.
  if (tid < 256) {
    int strip = tid >> 4, w4 = (tid & 15) * 4;
    int h0 = strip * 4;
    float4 a0 = make_float4(0.f, 0.f, 0.f, 0.f), a1 = a0, a2 = a0, a3 = a0;
#pragma unroll
    for (int j = 0; j < 35; ++j) {
      int r = h0 + j - 16;
      bool valid = (r >= 0) && (r < 64);
      int rc = valid ? r : 0;
      float4 f = *reinterpret_cast<const float4*>(&sp[rc * 68 + w4]);
      f.x = valid ? f.x : 0.0f; f.y = valid ? f.y : 0.0f;
      f.z = valid ? f.z : 0.0f; f.w = valid ? f.w : 0.0f;
      if (j <= 31) { a0.x += f.x; a0.y += f.y; a0.z += f.z; a0.w += f.w; }
      if (j >= 1 && j <= 32) { a1.x += f.x; a1.y += f.y; a1.z += f.z; a1.w += f.w; }
      if (j >= 2 && j <= 33) { a2.x += f.x; a2.y += f.y; a2.z += f.z; a2.w += f.w; }
      if (j >= 3) { a3.x += f.x; a3.y += f.y; a3.z += f.z; a3.w += f.w; }
    }
    *reinterpret_cast<float4*>(&cb[(h0 + 0) * 100 + 16 + w4]) = a0;
    *reinterpret_cast<float4*>(&cb[(h0 + 1) * 100 + 16 + w4]) = a1;
    *reinterpret_cast<float4*>(&cb[(h0 + 2) * 100 + 16 + w4]) = a2;
    *reinterpret_cast<float4*>(&cb[(h0 + 3) * 100 + 16 + w4]) = a3;
  } else if (tid < 768) {
    int l = tid - 256;                // 512 threads, 512 pad float4s
    int row = l >> 3, gq = l & 7;
    int base = row * 100 + ((gq < 4) ? gq * 4 : 80 + (gq - 4) * 4);
    *reinterpret_cast<float4*>(&cb[base]) = make_float4(0.f, 0.f, 0.f, 0.f);
  }
  __syncthreads();

  // phase 4: row window sums + argmax, on-the-fly accumulation (ascending u per d)
  float best = -3.402823466e+38f;
  int bidx = 0x7fffffff;
  {
    int h = tid >> 4, w4 = (tid & 15) * 4;
    float s0 = 0.f, s1 = 0.f, s2 = 0.f, s3 = 0.f;
#pragma unroll
    for (int q = 0; q < 9; ++q) {
      float4 f = *reinterpret_cast<const float4*>(&cb[h * 100 + w4 + 4 * q]);
      float fe[4] = {f.x, f.y, f.z, f.w};
#pragma unroll
      for (int e = 0; e < 4; ++e) {
        int u = 4 * q + e;
        if (u <= 31) s0 += fe[e];
        if (u >= 1 && u <= 32) s1 += fe[e];
        if (u >= 2 && u <= 33) s2 += fe[e];
        if (u >= 3 && u <= 34) s3 += fe[e];
      }
    }
    float sv[4] = {s0, s1, s2, s3};
#pragma unroll
    for (int d = 0; d < 4; ++d) {
      int i = (h << 6) + w4 + d;
      if (sv[d] > best) { best = sv[d]; bidx = i; }
    }
  }
#pragma unroll
  for (int off = 32; off > 0; off >>= 1) {
    float v2 = __shfl_down(best, off);
    int i2 = __shfl_down(bidx, off);
    if (v2 > best || (v2 == best && i2 < bidx)) { best = v2; bidx = i2; }
  }
  if ((tid & 63) == 0) { wv[tid >> 6] = best; wi[tid >> 6] = bidx; }
  __syncthreads();
  if (tid == 0) {
    float bv = wv[0]; int bi = wi[0];
#pragma unroll
    for (int k = 1; k < 16; ++k)
      if (wv[k] > bv || (wv[k] == bv && wi[k] < bi)) { bv = wv[k]; bi = wi[k]; }
    am_s = bi;
  }
  __syncthreads();

  // phase 5: 32x32 windowed gather (row+col clip via predicate)
  int am = am_s;
  int r = am >> 6, cx = am & 63;
  float* o = out + (size_t)bc * 1024;
  {
    int oi = tid >> 5, oj = tid & 31;
    int rr = r + oi - 16, cj = cx + oj - 16;
    bool v = (rr >= 0) && (rr < 64) && (cj >= 0) && (cj < 64);
    int rrc = v ? rr : 0, cjc = v ? cj : 0;
    o[tid] = v ? sp[rrc * 68 + cjc] : 0.0f;
  }
}

// ---------------- fused 32x32 layer: GEMM (4 ch/block) + sample + optional pool ----
template <bool POOL>
__global__ __launch_bounds__(256) void fused32_kernel(
    const float* __restrict__ lin, const float* __restrict__ x,
    const float* __restrict__ geo, const float* __restrict__ box,
    float* __restrict__ out, float* __restrict__ pooled) {
  const int H = 32, W = 32, HW = 1024;
  __shared__ __align__(16) float pls[4][1024];
  __shared__ float wred[16];
  int b = blockIdx.x >> 5;
  int c0 = (blockIdx.x & 31) * 4;
  int tid = threadIdx.x;
  const float* xb = x + (size_t)b * 128 * HW;
  const float* l0 = lin + (c0 + 0) * 128;
  const float* l1 = lin + (c0 + 1) * 128;
  const float* l2 = lin + (c0 + 2) * 128;
  const float* l3 = lin + (c0 + 3) * 128;
  int px4 = tid * 4;

  float4 acc0 = make_float4(0.f, 0.f, 0.f, 0.f);
  float4 acc1 = acc0, acc2 = acc0, acc3 = acc0;
#pragma unroll 8
  for (int k = 0; k < 128; ++k) {
    float4 xv = *reinterpret_cast<const float4*>(&xb[(size_t)k * HW + px4]);
    float s0 = l0[k], s1 = l1[k], s2 = l2[k], s3 = l3[k];
    acc0.x += s0 * xv.x; acc0.y += s0 * xv.y; acc0.z += s0 * xv.z; acc0.w += s0 * xv.w;
    acc1.x += s1 * xv.x; acc1.y += s1 * xv.y; acc1.z += s1 * xv.z; acc1.w += s1 * xv.w;
    acc2.x += s2 * xv.x; acc2.y += s2 * xv.y; acc2.z += s2 * xv.z; acc2.w += s2 * xv.w;
    acc3.x += s3 * xv.x; acc3.y += s3 * xv.y; acc3.z += s3 * xv.z; acc3.w += s3 * xv.w;
  }
  *reinterpret_cast<float4*>(&pls[0][px4]) = acc0;
  *reinterpret_cast<float4*>(&pls[1][px4]) = acc1;
  *reinterpret_cast<float4*>(&pls[2][px4]) = acc2;
  *reinterpret_cast<float4*>(&pls[3][px4]) = acc3;
  __syncthreads();

  float psum[4] = {0.f, 0.f, 0.f, 0.f};
#pragma unroll
  for (int c = 0; c < 4; ++c) {
    const float* g = geo + (c0 + c) * 6;
    const float* bxp = box + (c0 + c) * 6;
    float g0 = g[0], g1 = g[1], g2 = g[2], g3 = g[3], g4 = g[4], g5 = g[5];
    float b0 = bxp[0], b1 = bxp[1], b2 = bxp[2], b3 = bxp[3], b4 = bxp[4], b5 = bxp[5];
    float* o = out + ((size_t)b * CC + c0 + c) * HW;
    const float* pl = pls[c];
#pragma unroll
    for (int k = 0; k < 4; ++k) {
      int px = tid + k * 256;
      int h = px >> 5, w = px & 31;
      float xs = (2.0f * w + 1.0f) / W - 1.0f;
      float ys = (2.0f * h + 1.0f) / H - 1.0f;
      float gx = g0 * xs + g1 * ys + g2;
      float gy = g3 * xs + g4 * ys + g5;
      float ix = ((gx + 1.0f) * W - 1.0f) * 0.5f;
      float iy = ((gy + 1.0f) * H - 1.0f) * 0.5f;
      float x0 = floorf(ix), y0 = floorf(iy);
      float wx = ix - x0, wy = iy - y0;
      float v[2][2];
#pragma unroll
      for (int dy = 0; dy < 2; ++dy)
#pragma unroll
        for (int dx = 0; dx < 2; ++dx) {
          float xf = x0 + dx, yf = y0 + dy;
          bool valid = (xf >= 0.0f) && (xf <= 31.0f) && (yf >= 0.0f) && (yf <= 31.0f);
          int xi = (int)fminf(fmaxf(xf, 0.0f), 31.0f);
          int yi = (int)fminf(fmaxf(yf, 0.0f), 31.0f);
          v[dy][dx] = valid ? pl[yi * 32 + xi] : 0.0f;
        }
      float samp = (1.0f - wy) * ((1.0f - wx) * v[0][0] + wx * v[0][1]) +
                   wy * ((1.0f - wx) * v[1][0] + wx * v[1][1]);
      float bgx = b0 * xs + b1 * ys + b2;
      float bgy = b3 * xs + b4 * ys + b5;
      float bix = ((bgx + 1.0f) * W - 1.0f) * 0.5f;
      float biy = ((bgy + 1.0f) * H - 1.0f) * 0.5f;
      float bx0 = floorf(bix), by0 = floorf(biy);
      float bwx = bix - bx0, bwy = biy - by0;
      float m[2][2];
#pragma unroll
      for (int dy = 0; dy < 2; ++dy)
#pragma unroll
        for (int dx = 0; dx < 2; ++dx) {
          float xf = bx0 + dx, yf = by0 + dy;
          m[dy][dx] = ((xf >= 0.0f) && (xf <= 31.0f) && (yf >= 0.0f) && (yf <= 31.0f)) ? 1.0f : 0.0f;
        }
      float mask = (1.0f - bwy) * ((1.0f - bwx) * m[0][0] + bwx * m[0][1]) +
                   bwy * ((1.0f - bwx) * m[1][0] + bwx * m[1][1]);
      float res = samp * mask;
      o[px] = res;
      if (POOL) psum[c] += res;
    }
  }
  if (POOL) {
    int lane = tid & 63, wid = tid >> 6;
#pragma unroll
    for (int c = 0; c < 4; ++c) {
      float r = psum[c];
#pragma unroll
      for (int off = 32; off > 0; off >>= 1) r += __shfl_down(r, off);
      if (lane == 0) wred[c * 4 + wid] = r;
    }
    __syncthreads();
    if (tid < 4) {
      float t = wred[tid * 4] + wred[tid * 4 + 1] + wred[tid * 4 + 2] + wred[tid * 4 + 3];
      pooled[b * CC + c0 + tid] = t * (1.0f / 1024.0f);
    }
  }
}

// ---------------- dense head ----------------
__global__ __launch_bounds__(128) void dense_kernel(
    const float* __restrict__ pooled, const float* __restrict__ w,
    const float* __restrict__ bias, float* __restrict__ out) {
  int t = threadIdx.x;
  if (t < 80) {
    int b = t / 10, o = t % 10;
    float s = bias[o];
    const float* pb = pooled + b * 128;
    const float* wo = w + o * 128;
    for (int c = 0; c < 128; ++c) s += pb[c] * wo[c];
    out[b * 10 + o] = s;
  }
}

extern "C" void kernel_launch(void* const* d_in, const int* in_sizes, int n_in,
                              void* d_out, int out_size, void* d_ws, size_t ws_size,
                              hipStream_t stream) {
  const float* x     = (const float*)d_in[0];   // [8,3,64,64]
  const float* geo0  = (const float*)d_in[1];   // [128,2,3]
  const float* lin0  = (const float*)d_in[2];   // [128,3]
  const float* box0  = (const float*)d_in[3];   // [128,2,3]
  const float* geos  = (const float*)d_in[4];   // [3,128,2,3]
  const float* lins  = (const float*)d_in[5];   // [3,128,128]
  const float* boxes = (const float*)d_in[6];   // [3,128,2,3]
  const float* dw    = (const float*)d_in[7];   // [10,128]
  const float* db    = (const float*)d_in[8];   // [10]

  float* out  = (float*)d_out;      // [8,10] then feat [8,128,32,32]
  float* feat = out + 80;
  float* ws   = (float*)d_ws;
  float* ws0  = ws;                 // 16 MB
  float* ws1  = ws + 4194304;       // 16 MB
  float* pooled = ws + 8388608;     // 1024 floats

  // inLay: fused combine(Ci=3) + sample -> ws1
  inlay_sample_kernel<<<dim3(BB * CC), 256, 0, stream>>>(x, lin0, geo0, box0, ws1);
  // layer 0: combine (64x64 tiles) -> fused sample+maxpool -> 32x32
  gemm64_kernel<<<dim3(64, 2, BB), 256, 0, stream>>>(lins, ws1, ws0, 4096);
  sampmax_kernel<<<dim3(BB * CC), 1024, 0, stream>>>(ws0, geos, boxes, ws1);
  // layer 2: fused GEMM + sample
  fused32_kernel<false><<<dim3(256), 256, 0, stream>>>(lins + 16384, ws1, geos + 768, boxes + 768, ws0, nullptr);
  // layer 3: fused GEMM + sample + mean-pool, feat straight to d_out
  fused32_kernel<true><<<dim3(256), 256, 0, stream>>>(lins + 32768, ws0, geos + 1536, boxes + 1536, feat, pooled);
  // head
  dense_kernel<<<1, 128, 0, stream>>>(pooled, dw, db, out);
}

// Round 6
// 169.346 us; speedup vs baseline: 1.5143x; 1.0561x over previous
//
#include <hip/hip_runtime.h>

#define BB 8
#define CC 128

// ---------------- fused inLay: global->combine->LDS(stride 68) + sample + box mask ----
// Combine expression identical to prior rounds (w0*a + w1*b + w2*c) -> bit-identical.
__global__ __launch_bounds__(256) void inlay_sample_kernel(
    const float* __restrict__ x, const float* __restrict__ lin,
    const float* __restrict__ geo, const float* __restrict__ box,
    float* __restrict__ out) {
  const int H = 64, W = 64, HW = 4096;
  __shared__ __align__(16) float cp[64 * 68];   // 17.4 KB combined plane
  int bc = blockIdx.x;
  int c = bc & (CC - 1);
  int b = bc >> 7;
  int tid = threadIdx.x;
  const float* xb = x + (size_t)b * 3 * HW;

  float w0 = lin[c * 3 + 0], w1 = lin[c * 3 + 1], w2 = lin[c * 3 + 2];

  // phase 1: combine 3 input planes (coalesced global float4, L2-resident) -> cp
#pragma unroll
  for (int k = 0; k < 4; ++k) {
    int i4 = tid + k * 256;          // 0..1023 float4 groups
    int base = i4 * 4;
    float4 f0 = *reinterpret_cast<const float4*>(&xb[base]);
    float4 f1 = *reinterpret_cast<const float4*>(&xb[HW + base]);
    float4 f2 = *reinterpret_cast<const float4*>(&xb[2 * HW + base]);
    float4 cv;
    cv.x = w0 * f0.x + w1 * f1.x + w2 * f2.x;
    cv.y = w0 * f0.y + w1 * f1.y + w2 * f2.y;
    cv.z = w0 * f0.z + w1 * f1.z + w2 * f2.z;
    cv.w = w0 * f0.w + w1 * f1.w + w2 * f2.w;
    int h = i4 >> 4, w = (i4 & 15) * 4;
    *reinterpret_cast<float4*>(&cp[h * 68 + w]) = cv;
  }
  __syncthreads();

  const float* g = geo + c * 6;
  const float* bx = box + c * 6;
  float g0 = g[0], g1 = g[1], g2 = g[2], g3 = g[3], g4 = g[4], g5 = g[5];
  float b0 = bx[0], b1 = bx[1], b2 = bx[2], b3 = bx[3], b4 = bx[4], b5 = bx[5];
  float* o = out + ((size_t)b * CC + c) * HW;

  // phase 2: sample (4 taps, single combined plane)
#pragma unroll
  for (int k = 0; k < 16; ++k) {
    int px = tid + k * 256;
    int h = px >> 6, w = px & 63;
    float xs = (2.0f * w + 1.0f) / W - 1.0f;
    float ys = (2.0f * h + 1.0f) / H - 1.0f;
    float gx = g0 * xs + g1 * ys + g2;
    float gy = g3 * xs + g4 * ys + g5;
    float ix = ((gx + 1.0f) * W - 1.0f) * 0.5f;
    float iy = ((gy + 1.0f) * H - 1.0f) * 0.5f;
    float x0 = floorf(ix), y0 = floorf(iy);
    float wx = ix - x0, wy = iy - y0;
    float v[2][2];
#pragma unroll
    for (int dy = 0; dy < 2; ++dy)
#pragma unroll
      for (int dx = 0; dx < 2; ++dx) {
        float xf = x0 + dx, yf = y0 + dy;
        bool valid = (xf >= 0.0f) && (xf <= 63.0f) && (yf >= 0.0f) && (yf <= 63.0f);
        int xi = (int)fminf(fmaxf(xf, 0.0f), 63.0f);
        int yi = (int)fminf(fmaxf(yf, 0.0f), 63.0f);
        v[dy][dx] = valid ? cp[yi * 68 + xi] : 0.0f;
      }
    float samp = (1.0f - wy) * ((1.0f - wx) * v[0][0] + wx * v[0][1]) +
                 wy * ((1.0f - wx) * v[1][0] + wx * v[1][1]);

    float bgx = b0 * xs + b1 * ys + b2;
    float bgy = b3 * xs + b4 * ys + b5;
    float bix = ((bgx + 1.0f) * W - 1.0f) * 0.5f;
    float biy = ((bgy + 1.0f) * H - 1.0f) * 0.5f;
    float bx0 = floorf(bix), by0 = floorf(biy);
    float bwx = bix - bx0, bwy = biy - by0;
    float m[2][2];
#pragma unroll
    for (int dy = 0; dy < 2; ++dy)
#pragma unroll
      for (int dx = 0; dx < 2; ++dx) {
        float xf = bx0 + dx, yf = by0 + dy;
        m[dy][dx] = ((xf >= 0.0f) && (xf <= 63.0f) && (yf >= 0.0f) && (yf <= 63.0f)) ? 1.0f : 0.0f;
      }
    float mask = (1.0f - bwy) * ((1.0f - bwx) * m[0][0] + bwx * m[0][1]) +
                 bwy * ((1.0f - bwx) * m[1][0] + bwx * m[1][1]);
    o[px] = samp * mask;
  }
}

// ---------------- layer-0 GEMM: 64x64 tile, 4x4/thread, register prefetch ----------
__global__ __launch_bounds__(256) void gemm64_kernel(
    const float* __restrict__ lin, const float* __restrict__ x,
    float* __restrict__ y, int HW) {
  const int Ci = 128;
  __shared__ __align__(16) float As[16][68];
  __shared__ __align__(16) float Bs[16][64];
  int b = blockIdx.z;
  const float* xb = x + (size_t)b * Ci * HW;
  float* yb = y + (size_t)b * CC * HW;
  int tid = threadIdx.x;
  int tx = tid & 15, ty = tid >> 4;
  int row0 = blockIdx.y * 64;
  int col0 = blockIdx.x * 64;
  int m = tid >> 2, kq = (tid & 3) * 4;
  int kk = tid >> 4, n4 = (tid & 15) * 4;
  float acc[4][4] = {};
  float4 ra = *reinterpret_cast<const float4*>(&lin[(row0 + m) * Ci + kq]);
  float4 rb = *reinterpret_cast<const float4*>(&xb[(size_t)kk * HW + col0 + n4]);
  for (int k0 = 0; k0 < 128; k0 += 16) {
    __syncthreads();
    As[kq + 0][m] = ra.x; As[kq + 1][m] = ra.y; As[kq + 2][m] = ra.z; As[kq + 3][m] = ra.w;
    *reinterpret_cast<float4*>(&Bs[kk][n4]) = rb;
    __syncthreads();
    if (k0 + 16 < 128) {
      ra = *reinterpret_cast<const float4*>(&lin[(row0 + m) * Ci + k0 + 16 + kq]);
      rb = *reinterpret_cast<const float4*>(&xb[(size_t)(k0 + 16 + kk) * HW + col0 + n4]);
    }
#pragma unroll
    for (int kki = 0; kki < 16; ++kki) {
      float4 a4 = *reinterpret_cast<const float4*>(&As[kki][ty * 4]);
      float4 b4 = *reinterpret_cast<const float4*>(&Bs[kki][tx * 4]);
      float a[4] = {a4.x, a4.y, a4.z, a4.w};
      float bv[4] = {b4.x, b4.y, b4.z, b4.w};
#pragma unroll
      for (int i = 0; i < 4; i++)
#pragma unroll
        for (int j = 0; j < 4; j++) acc[i][j] += a[i] * bv[j];
    }
  }
#pragma unroll
  for (int i = 0; i < 4; i++) {
    float* yr = yb + (size_t)(row0 + ty * 4 + i) * HW + col0 + tx * 4;
    *reinterpret_cast<float4*>(yr) = make_float4(acc[i][0], acc[i][1], acc[i][2], acc[i][3]);
  }
}

// ---------------- fused sample(64x64) + MaxPool2d_G -> 32x32, 1024 threads ---------
// (1024, 4): VGPR cap 128 — round-5's (1024,8) forced <=64 and likely spilled.
__global__ __launch_bounds__(1024, 4) void sampmax_kernel(
    const float* __restrict__ y, const float* __restrict__ geo,
    const float* __restrict__ box, float* __restrict__ out) {
  __shared__ __align__(16) float sp[64 * 68];      // sampled plane, padded stride
  __shared__ __align__(16) float arena[64 * 100];  // pl (ph1-2) then cb (ph3-4)
  __shared__ float wv[16];
  __shared__ int wi[16];
  __shared__ int am_s;
  float* pl = arena;
  float* cb = arena;

  int bc = blockIdx.x;
  int c = bc & (CC - 1);
  int b = bc >> 7;
  int tid = threadIdx.x;

  // phase 1: load plane (contiguous 64-wide layout)
  const float* plane = y + (size_t)bc * 4096;
  *reinterpret_cast<float4*>(&pl[tid * 4]) = *reinterpret_cast<const float4*>(&plane[tid * 4]);
  __syncthreads();

  // phase 2: sample 4 px/thread -> sp
  {
    const float* g = geo + c * 6;
    const float* bx = box + c * 6;
    float g0 = g[0], g1 = g[1], g2 = g[2], g3 = g[3], g4 = g[4], g5 = g[5];
    float b0 = bx[0], b1 = bx[1], b2 = bx[2], b3 = bx[3], b4 = bx[4], b5 = bx[5];
#pragma unroll
    for (int k = 0; k < 4; ++k) {
      int px = tid + k * 1024;
      int h = px >> 6, w = px & 63;
      float xs = (2.0f * w + 1.0f) / 64.0f - 1.0f;
      float ys = (2.0f * h + 1.0f) / 64.0f - 1.0f;
      float gx = g0 * xs + g1 * ys + g2;
      float gy = g3 * xs + g4 * ys + g5;
      float ix = ((gx + 1.0f) * 64.0f - 1.0f) * 0.5f;
      float iy = ((gy + 1.0f) * 64.0f - 1.0f) * 0.5f;
      float x0 = floorf(ix), y0 = floorf(iy);
      float wx = ix - x0, wy = iy - y0;
      float v[2][2];
#pragma unroll
      for (int dy = 0; dy < 2; ++dy)
#pragma unroll
        for (int dx = 0; dx < 2; ++dx) {
          float xf = x0 + dx, yf = y0 + dy;
          bool valid = (xf >= 0.0f) && (xf <= 63.0f) && (yf >= 0.0f) && (yf <= 63.0f);
          int xi = (int)fminf(fmaxf(xf, 0.0f), 63.0f);
          int yi = (int)fminf(fmaxf(yf, 0.0f), 63.0f);
          v[dy][dx] = valid ? pl[yi * 64 + xi] : 0.0f;
        }
      float samp = (1.0f - wy) * ((1.0f - wx) * v[0][0] + wx * v[0][1]) +
                   wy * ((1.0f - wx) * v[1][0] + wx * v[1][1]);
      float bgx = b0 * xs + b1 * ys + b2;
      float bgy = b3 * xs + b4 * ys + b5;
      float bix = ((bgx + 1.0f) * 64.0f - 1.0f) * 0.5f;
      float biy = ((bgy + 1.0f) * 64.0f - 1.0f) * 0.5f;
      float bx0 = floorf(bix), by0 = floorf(biy);
      float bwx = bix - bx0, bwy = biy - by0;
      float m[2][2];
#pragma unroll
      for (int dy = 0; dy < 2; ++dy)
#pragma unroll
        for (int dx = 0; dx < 2; ++dx) {
          float xf = bx0 + dx, yf = by0 + dy;
          m[dy][dx] = ((xf >= 0.0f) && (xf <= 63.0f) && (yf >= 0.0f) && (yf <= 63.0f)) ? 1.0f : 0.0f;
        }
      float mask = (1.0f - bwy) * ((1.0f - bwx) * m[0][0] + bwx * m[0][1]) +
                   bwy * ((1.0f - bwx) * m[1][0] + bwx * m[1][1]);
      sp[h * 68 + w] = samp * mask;
    }
  }
  __syncthreads();   // pl dead; cb (same arena) written next

  // phase 3: column band sums. strips of 4 output rows (threads 0..255);
  // threads 256..767 zero cb's side pads. Row clip via masked exact-0 adds.
  if (tid < 256) {
    int strip = tid >> 4, w4 = (tid & 15) * 4;
    int h0 = strip * 4;
    float4 a0 = make_float4(0.f, 0.f, 0.f, 0.f), a1 = a0, a2 = a0, a3 = a0;
#pragma unroll
    for (int j = 0; j < 35; ++j) {
      int r = h0 + j - 16;
      bool valid = (r >= 0) && (r < 64);
      int rc = valid ? r : 0;
      float4 f = *reinterpret_cast<const float4*>(&sp[rc * 68 + w4]);
      f.x = valid ? f.x : 0.0f; f.y = valid ? f.y : 0.0f;
      f.z = valid ? f.z : 0.0f; f.w = valid ? f.w : 0.0f;
      if (j <= 31) { a0.x += f.x; a0.y += f.y; a0.z += f.z; a0.w += f.w; }
      if (j >= 1 && j <= 32) { a1.x += f.x; a1.y += f.y; a1.z += f.z; a1.w += f.w; }
      if (j >= 2 && j <= 33) { a2.x += f.x; a2.y += f.y; a2.z += f.z; a2.w += f.w; }
      if (j >= 3) { a3.x += f.x; a3.y += f.y; a3.z += f.z; a3.w += f.w; }
    }
    *reinterpret_cast<float4*>(&cb[(h0 + 0) * 100 + 16 + w4]) = a0;
    *reinterpret_cast<float4*>(&cb[(h0 + 1) * 100 + 16 + w4]) = a1;
    *reinterpret_cast<float4*>(&cb[(h0 + 2) * 100 + 16 + w4]) = a2;
    *reinterpret_cast<float4*>(&cb[(h0 + 3) * 100 + 16 + w4]) = a3;
  } else if (tid < 768) {
    int l = tid - 256;                // 512 threads, 512 pad float4s
    int row = l >> 3, gq = l & 7;
    int base = row * 100 + ((gq < 4) ? gq * 4 : 80 + (gq - 4) * 4);
    *reinterpret_cast<float4*>(&cb[base]) = make_float4(0.f, 0.f, 0.f, 0.f);
  }
  __syncthreads();

  // phase 4: row window sums + argmax, on-the-fly accumulation (ascending u per d)
  float best = -3.402823466e+38f;
  int bidx = 0x7fffffff;
  {
    int h = tid >> 4, w4 = (tid & 15) * 4;
    float s0 = 0.f, s1 = 0.f, s2 = 0.f, s3 = 0.f;
#pragma unroll
    for (int q = 0; q < 9; ++q) {
      float4 f = *reinterpret_cast<const float4*>(&cb[h * 100 + w4 + 4 * q]);
      float fe[4] = {f.x, f.y, f.z, f.w};
#pragma unroll
      for (int e = 0; e < 4; ++e) {
        int u = 4 * q + e;
        if (u <= 31) s0 += fe[e];
        if (u >= 1 && u <= 32) s1 += fe[e];
        if (u >= 2 && u <= 33) s2 += fe[e];
        if (u >= 3 && u <= 34) s3 += fe[e];
      }
    }
    float sv[4] = {s0, s1, s2, s3};
#pragma unroll
    for (int d = 0; d < 4; ++d) {
      int i = (h << 6) + w4 + d;
      if (sv[d] > best) { best = sv[d]; bidx = i; }
    }
  }
#pragma unroll
  for (int off = 32; off > 0; off >>= 1) {
    float v2 = __shfl_down(best, off);
    int i2 = __shfl_down(bidx, off);
    if (v2 > best || (v2 == best && i2 < bidx)) { best = v2; bidx = i2; }
  }
  if ((tid & 63) == 0) { wv[tid >> 6] = best; wi[tid >> 6] = bidx; }
  __syncthreads();
  if (tid == 0) {
    float bv = wv[0]; int bi = wi[0];
#pragma unroll
    for (int k = 1; k < 16; ++k)
      if (wv[k] > bv || (wv[k] == bv && wi[k] < bi)) { bv = wv[k]; bi = wi[k]; }
    am_s = bi;
  }
  __syncthreads();

  // phase 5: 32x32 windowed gather (row+col clip via predicate)
  int am = am_s;
  int r = am >> 6, cx = am & 63;
  float* o = out + (size_t)bc * 1024;
  {
    int oi = tid >> 5, oj = tid & 31;
    int rr = r + oi - 16, cj = cx + oj - 16;
    bool v = (rr >= 0) && (rr < 64) && (cj >= 0) && (cj < 64);
    int rrc = v ? rr : 0, cjc = v ? cj : 0;
    o[tid] = v ? sp[rrc * 68 + cjc] : 0.0f;
  }
}

// ---------------- fused 32x32 layer: GEMM (4 ch/block) + sample + optional pool ----
template <bool POOL>
__global__ __launch_bounds__(256) void fused32_kernel(
    const float* __restrict__ lin, const float* __restrict__ x,
    const float* __restrict__ geo, const float* __restrict__ box,
    float* __restrict__ out, float* __restrict__ pooled) {
  const int H = 32, W = 32, HW = 1024;
  __shared__ __align__(16) float pls[4][1024];
  __shared__ float wred[16];
  int b = blockIdx.x >> 5;
  int c0 = (blockIdx.x & 31) * 4;
  int tid = threadIdx.x;
  const float* xb = x + (size_t)b * 128 * HW;
  const float* l0 = lin + (c0 + 0) * 128;
  const float* l1 = lin + (c0 + 1) * 128;
  const float* l2 = lin + (c0 + 2) * 128;
  const float* l3 = lin + (c0 + 3) * 128;
  int px4 = tid * 4;

  float4 acc0 = make_float4(0.f, 0.f, 0.f, 0.f);
  float4 acc1 = acc0, acc2 = acc0, acc3 = acc0;
#pragma unroll 8
  for (int k = 0; k < 128; ++k) {
    float4 xv = *reinterpret_cast<const float4*>(&xb[(size_t)k * HW + px4]);
    float s0 = l0[k], s1 = l1[k], s2 = l2[k], s3 = l3[k];
    acc0.x += s0 * xv.x; acc0.y += s0 * xv.y; acc0.z += s0 * xv.z; acc0.w += s0 * xv.w;
    acc1.x += s1 * xv.x; acc1.y += s1 * xv.y; acc1.z += s1 * xv.z; acc1.w += s1 * xv.w;
    acc2.x += s2 * xv.x; acc2.y += s2 * xv.y; acc2.z += s2 * xv.z; acc2.w += s2 * xv.w;
    acc3.x += s3 * xv.x; acc3.y += s3 * xv.y; acc3.z += s3 * xv.z; acc3.w += s3 * xv.w;
  }
  *reinterpret_cast<float4*>(&pls[0][px4]) = acc0;
  *reinterpret_cast<float4*>(&pls[1][px4]) = acc1;
  *reinterpret_cast<float4*>(&pls[2][px4]) = acc2;
  *reinterpret_cast<float4*>(&pls[3][px4]) = acc3;
  __syncthreads();

  float psum[4] = {0.f, 0.f, 0.f, 0.f};
#pragma unroll
  for (int c = 0; c < 4; ++c) {
    const float* g = geo + (c0 + c) * 6;
    const float* bxp = box + (c0 + c) * 6;
    float g0 = g[0], g1 = g[1], g2 = g[2], g3 = g[3], g4 = g[4], g5 = g[5];
    float b0 = bxp[0], b1 = bxp[1], b2 = bxp[2], b3 = bxp[3], b4 = bxp[4], b5 = bxp[5];
    float* o = out + ((size_t)b * CC + c0 + c) * HW;
    const float* pl = pls[c];
#pragma unroll
    for (int k = 0; k < 4; ++k) {
      int px = tid + k * 256;
      int h = px >> 5, w = px & 31;
      float xs = (2.0f * w + 1.0f) / W - 1.0f;
      float ys = (2.0f * h + 1.0f) / H - 1.0f;
      float gx = g0 * xs + g1 * ys + g2;
      float gy = g3 * xs + g4 * ys + g5;
      float ix = ((gx + 1.0f) * W - 1.0f) * 0.5f;
      float iy = ((gy + 1.0f) * H - 1.0f) * 0.5f;
      float x0 = floorf(ix), y0 = floorf(iy);
      float wx = ix - x0, wy = iy - y0;
      float v[2][2];
#pragma unroll
      for (int dy = 0; dy < 2; ++dy)
#pragma unroll
        for (int dx = 0; dx < 2; ++dx) {
          float xf = x0 + dx, yf = y0 + dy;
          bool valid = (xf >= 0.0f) && (xf <= 31.0f) && (yf >= 0.0f) && (yf <= 31.0f);
          int xi = (int)fminf(fmaxf(xf, 0.0f), 31.0f);
          int yi = (int)fminf(fmaxf(yf, 0.0f), 31.0f);
          v[dy][dx] = valid ? pl[yi * 32 + xi] : 0.0f;
        }
      float samp = (1.0f - wy) * ((1.0f - wx) * v[0][0] + wx * v[0][1]) +
                   wy * ((1.0f - wx) * v[1][0] + wx * v[1][1]);
      float bgx = b0 * xs + b1 * ys + b2;
      float bgy = b3 * xs + b4 * ys + b5;
      float bix = ((bgx + 1.0f) * W - 1.0f) * 0.5f;
      float biy = ((bgy + 1.0f) * H - 1.0f) * 0.5f;
      float bx0 = floorf(bix), by0 = floorf(biy);
      float bwx = bix - bx0, bwy = biy - by0;
      float m[2][2];
#pragma unroll
      for (int dy = 0; dy < 2; ++dy)
#pragma unroll
        for (int dx = 0; dx < 2; ++dx) {
          float xf = bx0 + dx, yf = by0 + dy;
          m[dy][dx] = ((xf >= 0.0f) && (xf <= 31.0f) && (yf >= 0.0f) && (yf <= 31.0f)) ? 1.0f : 0.0f;
        }
      float mask = (1.0f - bwy) * ((1.0f - bwx) * m[0][0] + bwx * m[0][1]) +
                   bwy * ((1.0f - bwx) * m[1][0] + bwx * m[1][1]);
      float res = samp * mask;
      o[px] = res;
      if (POOL) psum[c] += res;
    }
  }
  if (POOL) {
    int lane = tid & 63, wid = tid >> 6;
#pragma unroll
    for (int c = 0; c < 4; ++c) {
      float r = psum[c];
#pragma unroll
      for (int off = 32; off > 0; off >>= 1) r += __shfl_down(r, off);
      if (lane == 0) wred[c * 4 + wid] = r;
    }
    __syncthreads();
    if (tid < 4) {
      float t = wred[tid * 4] + wred[tid * 4 + 1] + wred[tid * 4 + 2] + wred[tid * 4 + 3];
      pooled[b * CC + c0 + tid] = t * (1.0f / 1024.0f);
    }
  }
}

// ---------------- dense head ----------------
__global__ __launch_bounds__(128) void dense_kernel(
    const float* __restrict__ pooled, const float* __restrict__ w,
    const float* __restrict__ bias, float* __restrict__ out) {
  int t = threadIdx.x;
  if (t < 80) {
    int b = t / 10, o = t % 10;
    float s = bias[o];
    const float* pb = pooled + b * 128;
    const float* wo = w + o * 128;
    for (int c = 0; c < 128; ++c) s += pb[c] * wo[c];
    out[b * 10 + o] = s;
  }
}

extern "C" void kernel_launch(void* const* d_in, const int* in_sizes, int n_in,
                              void* d_out, int out_size, void* d_ws, size_t ws_size,
                              hipStream_t stream) {
  const float* x     = (const float*)d_in[0];   // [8,3,64,64]
  const float* geo0  = (const float*)d_in[1];   // [128,2,3]
  const float* lin0  = (const float*)d_in[2];   // [128,3]
  const float* box0  = (const float*)d_in[3];   // [128,2,3]
  const float* geos  = (const float*)d_in[4];   // [3,128,2,3]
  const float* lins  = (const float*)d_in[5];   // [3,128,128]
  const float* boxes = (const float*)d_in[6];   // [3,128,2,3]
  const float* dw    = (const float*)d_in[7];   // [10,128]
  const float* db    = (const float*)d_in[8];   // [10]

  float* out  = (float*)d_out;      // [8,10] then feat [8,128,32,32]
  float* feat = out + 80;
  float* ws   = (float*)d_ws;
  float* ws0  = ws;                 // 16 MB
  float* ws1  = ws + 4194304;       // 16 MB
  float* pooled = ws + 8388608;     // 1024 floats

  // inLay: fused combine(Ci=3) + sample -> ws1
  inlay_sample_kernel<<<dim3(BB * CC), 256, 0, stream>>>(x, lin0, geo0, box0, ws1);
  // layer 0: combine (64x64 tiles) -> fused sample+maxpool -> 32x32
  gemm64_kernel<<<dim3(64, 2, BB), 256, 0, stream>>>(lins, ws1, ws0, 4096);
  sampmax_kernel<<<dim3(BB * CC), 1024, 0, stream>>>(ws0, geos, boxes, ws1);
  // layer 2: fused GEMM + sample
  fused32_kernel<false><<<dim3(256), 256, 0, stream>>>(lins + 16384, ws1, geos + 768, boxes + 768, ws0, nullptr);
  // layer 3: fused GEMM + sample + mean-pool, feat straight to d_out
  fused32_kernel<true><<<dim3(256), 256, 0, stream>>>(lins + 32768, ws0, geos + 1536, boxes + 1536, feat, pooled);
  // head
  dense_kernel<<<1, 128, 0, stream>>>(pooled, dw, db, out);
}